// Round 11
// baseline (463.120 us; speedup 1.0000x reference)
//
#include <hip/hip_runtime.h>
#include <cfloat>

#define NN     16384
#define NEDGE  262144
#define HD     128
#define NLAYER 3
#define NRED   8192
#define LATD   64
#define GDIM   32
#define RCS    256   // combined row/col table stride (shorts)

typedef __attribute__((ext_vector_type(8))) short short8;
typedef __attribute__((ext_vector_type(4))) float f32x4;

__device__ __forceinline__ unsigned short f2bf(float f) {
    union { float f; unsigned u; } v; v.f = f;
    unsigned u = v.u;
    unsigned r = u + 0x7fff + ((u >> 16) & 1);
    return (unsigned short)(r >> 16);
}
__device__ __forceinline__ void unp8(uint4 v, float* f) {
    unsigned w0=v.x, w1=v.y, w2=v.z, w3=v.w;
    f[0]=__uint_as_float(w0<<16); f[1]=__uint_as_float(w0&0xffff0000u);
    f[2]=__uint_as_float(w1<<16); f[3]=__uint_as_float(w1&0xffff0000u);
    f[4]=__uint_as_float(w2<<16); f[5]=__uint_as_float(w2&0xffff0000u);
    f[6]=__uint_as_float(w3<<16); f[7]=__uint_as_float(w3&0xffff0000u);
}
__device__ __forceinline__ unsigned long long umin64(unsigned long long a, unsigned long long b) {
    return a < b ? a : b;
}
__device__ __forceinline__ unsigned long long umax64(unsigned long long a, unsigned long long b) {
    return a < b ? b : a;
}

// ---------------------------------------------------------------- consolidated weight packing
__device__ __forceinline__ unsigned short pack_std(const float* W, int ksteps, int q) {
    int j    = q & 7;
    int lane = (q >> 3) & 63;
    int ks   = (q >> 9) % ksteps;
    int nt   = q / (ksteps * 512);
    int k = ks*32 + (lane >> 4)*8 + j;
    int n = nt*16 + (lane & 15);
    return f2bf(W[k*128 + n]);
}
__device__ __forceinline__ unsigned short pack_w2e(const float* W, int q) {
    int j    = q & 7;
    int lane = (q >> 3) & 63;
    int ks   = q >> 9;
    int k = ks*32 + (lane >> 4)*8 + j;
    int n = lane & 15;
    return (n < 2) ? f2bf(W[k*2 + n]) : (unsigned short)0;
}

#define PK_TOTAL 448512
__global__ __launch_bounds__(256) void k_pack_all(
    const float* __restrict__ msgw1, const float* __restrict__ msgw2,
    const float* __restrict__ edgew1, const float* __restrict__ nodew1,
    const float* __restrict__ nodew2, const float* __restrict__ edgew2,
    const float* __restrict__ m0w2, const float* __restrict__ m2w1,
    const float* __restrict__ m2w2, unsigned short* __restrict__ P)
{
    int p = blockIdx.x*256 + threadIdx.x;
    if (p >= PK_TOTAL) return;
    unsigned short v;
    if (p < 98304) {
        int l = p / 32768, q = p % 32768;
        v = pack_std(msgw1 + (size_t)l*258*128, 8, q);
    } else if (p < 147456) {
        int t = p - 98304; int l = t / 16384, q = t % 16384;
        v = pack_std(msgw2 + (size_t)l*16384, 4, q);
    } else if (p < 245760) {
        int t = p - 147456; int l = t / 32768, q = t % 32768;
        v = pack_std(edgew1 + (size_t)l*258*128, 8, q);
    } else if (p < 344064) {
        int t = p - 245760; int l = t / 32768, q = t % 32768;
        v = pack_std(nodew1 + (size_t)l*256*128, 8, q);
    } else if (p < 393216) {
        int t = p - 344064; int l = t / 16384, q = t % 16384;
        v = pack_std(nodew2 + (size_t)l*16384, 4, q);
    } else if (p < 399360) {
        int t = p - 393216; int l = t / 2048, q = t % 2048;
        v = pack_w2e(edgew2 + (size_t)l*256, q);
    } else if (p < 415744) {
        v = pack_std(m0w2, 4, p - 399360);
    } else if (p < 432128) {
        v = pack_std(m2w1, 4, p - 415744);
    } else {
        v = pack_std(m2w2, 4, p - 432128);
    }
    P[p] = v;
}

union HUu { unsigned short Hs[64][136]; uint4 UF4[1024]; };

// ---------------------------------------------------------------- stage 1: node encoder + msg-table precompute (RT/CT high half) + agg zero
__global__ __launch_bounds__(256) void k_nenc_mfma(
    const float* __restrict__ x,
    const float* __restrict__ w1, const float* __restrict__ b1,
    const unsigned short* __restrict__ W2p, const float* __restrict__ B2,
    const float* __restrict__ lg, const float* __restrict__ lb,
    const unsigned short* __restrict__ mW1p, const float* __restrict__ mB1,
    float* __restrict__ u, unsigned short* __restrict__ u16,
    unsigned short* __restrict__ RT, unsigned short* __restrict__ CT,
    float* __restrict__ agg)
{
    __shared__ float xs[64][4];
    __shared__ float w1s[3][128];
    __shared__ float b1s[128];
    __shared__ HUu HU;
    __shared__ float Rs[64][132];
    __shared__ float red[64][4];
    __shared__ float mstat[64], sstat[64];
    int tid = threadIdx.x;
    int n0  = blockIdx.x * 64;
    {
        float4 z; z.x=0.f; z.y=0.f; z.z=0.f; z.w=0.f;
        for (int t = tid; t < 2048; t += 256)
            *(float4*)(agg + (size_t)(n0 + (t>>5))*HD + (t&31)*4) = z;
    }
    for (int t = tid; t < 384; t += 256) w1s[t >> 7][t & 127] = w1[t];
    if (tid < 128) b1s[tid] = b1[tid];
    for (int t = tid; t < 192; t += 256) xs[t/3][t%3] = x[(size_t)n0*3 + t];
    __syncthreads();
    {
        int m = tid >> 2, p0 = (tid & 3) * 32;
        float x0 = xs[m][0], x1 = xs[m][1], x2 = xs[m][2];
        for (int j = p0; j < p0 + 32; j += 2) {
            float h0 = fmaxf(b1s[j]   + x0*w1s[0][j]   + x1*w1s[1][j]   + x2*w1s[2][j],   0.f);
            float h1 = fmaxf(b1s[j+1] + x0*w1s[0][j+1] + x1*w1s[1][j+1] + x2*w1s[2][j+1], 0.f);
            *(unsigned*)&HU.Hs[m][j] = f2bf(h0) | ((unsigned)f2bf(h1) << 16);
        }
    }
    __syncthreads();

    int lane = tid & 63, wave = tid >> 6;
    int lr = lane & 15, lq = lane >> 4;
    f32x4 acc[8];
    #pragma unroll
    for (int i = 0; i < 8; ++i) acc[i] = (f32x4){0.f,0.f,0.f,0.f};
    for (int ks = 0; ks < 4; ++ks) {
        short8 a0 = *(const short8*)&HU.Hs[ 0 + lr][ks*32 + lq*8];
        short8 a1 = *(const short8*)&HU.Hs[16 + lr][ks*32 + lq*8];
        short8 a2 = *(const short8*)&HU.Hs[32 + lr][ks*32 + lq*8];
        short8 a3 = *(const short8*)&HU.Hs[48 + lr][ks*32 + lq*8];
        short8 b0 = *(const short8*)(W2p + (size_t)(((wave*2+0)*4 + ks)*64 + lane)*8);
        short8 b1v= *(const short8*)(W2p + (size_t)(((wave*2+1)*4 + ks)*64 + lane)*8);
        acc[0] = __builtin_amdgcn_mfma_f32_16x16x32_bf16(a0, b0, acc[0], 0,0,0);
        acc[1] = __builtin_amdgcn_mfma_f32_16x16x32_bf16(a0, b1v, acc[1], 0,0,0);
        acc[2] = __builtin_amdgcn_mfma_f32_16x16x32_bf16(a1, b0, acc[2], 0,0,0);
        acc[3] = __builtin_amdgcn_mfma_f32_16x16x32_bf16(a1, b1v, acc[3], 0,0,0);
        acc[4] = __builtin_amdgcn_mfma_f32_16x16x32_bf16(a2, b0, acc[4], 0,0,0);
        acc[5] = __builtin_amdgcn_mfma_f32_16x16x32_bf16(a2, b1v, acc[5], 0,0,0);
        acc[6] = __builtin_amdgcn_mfma_f32_16x16x32_bf16(a3, b0, acc[6], 0,0,0);
        acc[7] = __builtin_amdgcn_mfma_f32_16x16x32_bf16(a3, b1v, acc[7], 0,0,0);
    }
    #pragma unroll
    for (int b = 0; b < 2; ++b) {
        int n = (wave*2 + b)*16 + lr;
        float bb = B2[n];
        #pragma unroll
        for (int mt = 0; mt < 4; ++mt) {
            f32x4 v = acc[mt*2 + b];
            #pragma unroll
            for (int r = 0; r < 4; ++r) {
                int m = mt*16 + lq*4 + r;
                Rs[m][n] = v[r] + bb;
            }
        }
    }
    __syncthreads();
    {
        int m = tid >> 2, p = tid & 3;
        float s = 0.f;
        #pragma unroll 8
        for (int i = 0; i < 32; ++i) s += Rs[m][p*32 + i];
        red[m][p] = s;
    }
    __syncthreads();
    if (tid < 64) mstat[tid] = (red[tid][0]+red[tid][1]+red[tid][2]+red[tid][3]) * (1.f/HD);
    __syncthreads();
    {
        int m = tid >> 2, p = tid & 3;
        float mm = mstat[m];
        float s = 0.f;
        #pragma unroll 8
        for (int i = 0; i < 32; ++i) { float d = Rs[m][p*32 + i] - mm; s += d*d; }
        red[m][p] = s;
    }
    __syncthreads();
    if (tid < 64) sstat[tid] = sqrtf((red[tid][0]+red[tid][1]+red[tid][2]+red[tid][3]) * (1.f/HD) + 1e-5f);
    __syncthreads();
    for (int t = tid; t < 2048; t += 256) {
        int m = t >> 5, q = t & 31;
        int n = q*4;
        float mm = mstat[m], sd = sstat[m];
        float4 g4 = *(const float4*)(lg + n);
        float4 b4 = *(const float4*)(lb + n);
        float o0 = (Rs[m][n+0]-mm)/sd*g4.x + b4.x;
        float o1 = (Rs[m][n+1]-mm)/sd*g4.y + b4.y;
        float o2 = (Rs[m][n+2]-mm)/sd*g4.z + b4.z;
        float o3 = (Rs[m][n+3]-mm)/sd*g4.w + b4.w;
        float4 fo; fo.x=o0; fo.y=o1; fo.z=o2; fo.w=o3;
        *(float4*)(u + (size_t)(n0+m)*HD + n) = fo;
        uint2 pk; pk.x = f2bf(o0) | (f2bf(o1)<<16); pk.y = f2bf(o2) | (f2bf(o3)<<16);
        *(uint2*)(u16 + (size_t)(n0+m)*HD + n) = pk;
        int ksf = n >> 5, sub = (n >> 3) & 3;
        int slot = (ksf*4 + (m >> 4))*64 + ((m & 15) | (sub << 4));
        unsigned short* UF = (unsigned short*)HU.UF4;
        *(uint2*)&UF[slot*8 + (n & 7)] = pk;
    }
    __syncthreads();

    // msg tables: RT[n][128..256) = u·msgW1r ; CT[n][128..256) = u·msgW1c + mB1
    for (int g = 0; g < 2; ++g) {
        int ksOff = g*4;
        unsigned short* Out = (g ? CT : RT) + 128;
        #pragma unroll
        for (int i = 0; i < 8; ++i) acc[i] = (f32x4){0.f,0.f,0.f,0.f};
        for (int ks = 0; ks < 4; ++ks) {
            short8 a0 = *(const short8*)&HU.UF4[(ks*4+0)*64 + lane];
            short8 a1 = *(const short8*)&HU.UF4[(ks*4+1)*64 + lane];
            short8 a2 = *(const short8*)&HU.UF4[(ks*4+2)*64 + lane];
            short8 a3 = *(const short8*)&HU.UF4[(ks*4+3)*64 + lane];
            short8 b0 = *(const short8*)(mW1p + (size_t)(((wave*2+0)*8 + ksOff + ks)*64 + lane)*8);
            short8 b1v= *(const short8*)(mW1p + (size_t)(((wave*2+1)*8 + ksOff + ks)*64 + lane)*8);
            acc[0] = __builtin_amdgcn_mfma_f32_16x16x32_bf16(a0, b0, acc[0], 0,0,0);
            acc[1] = __builtin_amdgcn_mfma_f32_16x16x32_bf16(a0, b1v, acc[1], 0,0,0);
            acc[2] = __builtin_amdgcn_mfma_f32_16x16x32_bf16(a1, b0, acc[2], 0,0,0);
            acc[3] = __builtin_amdgcn_mfma_f32_16x16x32_bf16(a1, b1v, acc[3], 0,0,0);
            acc[4] = __builtin_amdgcn_mfma_f32_16x16x32_bf16(a2, b0, acc[4], 0,0,0);
            acc[5] = __builtin_amdgcn_mfma_f32_16x16x32_bf16(a2, b1v, acc[5], 0,0,0);
            acc[6] = __builtin_amdgcn_mfma_f32_16x16x32_bf16(a3, b0, acc[6], 0,0,0);
            acc[7] = __builtin_amdgcn_mfma_f32_16x16x32_bf16(a3, b1v, acc[7], 0,0,0);
        }
        #pragma unroll
        for (int b = 0; b < 2; ++b) {
            int n = (wave*2 + b)*16 + lr;
            float bb = g ? mB1[n] : 0.f;
            #pragma unroll
            for (int mt = 0; mt < 4; ++mt) {
                f32x4 v = acc[mt*2 + b];
                #pragma unroll
                for (int r = 0; r < 4; ++r) {
                    int rowp = n0 + mt*16 + lq*4 + r;
                    unsigned hv = f2bf(v[r] + bb);
                    unsigned ph = (unsigned)__shfl_xor((int)hv, 1, 64);
                    if (!(lr & 1))
                        *(unsigned*)&Out[(size_t)rowp*RCS + n] = hv | (ph << 16);
                }
            }
        }
    }
}

// ---------------------------------------------------------------- stage 2
__global__ __launch_bounds__(256) void k_edge_enc(
    const float* __restrict__ pos, const int* __restrict__ row, const int* __restrict__ col,
    const float* __restrict__ w1, const float* __restrict__ b1,
    const float* __restrict__ w2, const float* __restrict__ b2,
    const float* __restrict__ lg, const float* __restrict__ lb,
    float* __restrict__ ef)
{
    int e = blockIdx.x*256 + threadIdx.x;
    if (e >= NEDGE) return;
    int r = row[e], c = col[e];
    float e0 = pos[c*2]   - pos[r*2];
    float e1 = pos[c*2+1] - pos[r*2+1];
    float o0 = b2[0], o1 = b2[1];
    for (int j = 0; j < HD; ++j) {
        float h = fmaxf(e0*w1[j] + e1*w1[HD+j] + b1[j], 0.f);
        o0 += h*w2[j*2];
        o1 += h*w2[j*2+1];
    }
    float m  = 0.5f*(o0 + o1);
    float d0 = o0 - m, d1 = o1 - m;
    float v  = 0.5f*(d0*d0 + d1*d1);
    float sd = sqrtf(v + 1e-5f);
    ef[e*2]   = d0/sd*lg[0] + lb[0];
    ef[e*2+1] = d1/sd*lg[1] + lb[1];
}

// ---------------------------------------------------------------- merged counts
__global__ void k_count2(const int* __restrict__ col, const float* __restrict__ pos,
                         int* __restrict__ cnt, int* __restrict__ gcnt)
{
    int e = blockIdx.x*256 + threadIdx.x;
    if (e < NEDGE) atomicAdd(&cnt[col[e]], 1);
    if (e < NN) {
        int cx = min(max((int)(pos[e*2]  *(float)GDIM), 0), GDIM-1);
        int cy = min(max((int)(pos[e*2+1]*(float)GDIM), 0), GDIM-1);
        atomicAdd(&gcnt[cy*GDIM + cx], 1);
    }
}

// ---------------------------------------------------------------- merged scans
__global__ __launch_bounds__(256) void k_scan2(
    const int* __restrict__ cnt, int* __restrict__ head,
    const int* __restrict__ gcnt, int* __restrict__ gstart, int* __restrict__ ghead)
{
    __shared__ int ls[257];
    int tid = threadIdx.x;
    if (blockIdx.x == 0) {
        int base = tid * (NN/256);
        int s = 0;
        for (int i = 0; i < NN/256; ++i) s += cnt[base + i];
        ls[tid+1] = s;
        if (tid == 0) ls[0] = 0;
        __syncthreads();
        if (tid == 0) for (int i = 1; i <= 256; ++i) ls[i] += ls[i-1];
        __syncthreads();
        int run = ls[tid];
        for (int i = 0; i < NN/256; ++i) {
            head[base + i] = run;
            run += cnt[base + i];
        }
    } else {
        int base = tid * 4;
        int s = 0;
        for (int i = 0; i < 4; ++i) s += gcnt[base + i];
        ls[tid+1] = s;
        if (tid == 0) ls[0] = 0;
        __syncthreads();
        if (tid == 0) for (int i = 1; i <= 256; ++i) ls[i] += ls[i-1];
        __syncthreads();
        int run = ls[tid];
        for (int i = 0; i < 4; ++i) {
            gstart[base+i] = run; ghead[base+i] = run;
            run += gcnt[base+i];
        }
        if (tid == 255) gstart[GDIM*GDIM] = run;
    }
}

// ---------------------------------------------------------------- merged scatters
__global__ __launch_bounds__(256) void k_scatter2(
    const int* __restrict__ col, const float* __restrict__ pos,
    int* __restrict__ head, int* __restrict__ perm,
    int* __restrict__ ghead, float2* __restrict__ psort, int* __restrict__ pidx)
{
    int e = blockIdx.x*256 + threadIdx.x;
    if (e < NEDGE) {
        int p = atomicAdd(&head[col[e]], 1);
        perm[p] = e;
    }
    if (e < NN) {
        float px = pos[e*2], py = pos[e*2+1];
        int cx = min(max((int)(px*(float)GDIM), 0), GDIM-1);
        int cy = min(max((int)(py*(float)GDIM), 0), GDIM-1);
        int p = atomicAdd(&ghead[cy*GDIM + cx], 1);
        float2 pp; pp.x = px; pp.y = py;
        psort[p] = pp;
        pidx[p] = e;
    }
}

// ---------------------------------------------------------------- grid kNN select -> coef scatter
__global__ __launch_bounds__(256) void k_knnsel(
    const float* __restrict__ pos, const int* __restrict__ gstart,
    const float2* __restrict__ psort, const int* __restrict__ pidx,
    float* __restrict__ coef)
{
    int r = blockIdx.x*256 + threadIdx.x;
    int ni = (int)(2.0*r + (double)r/8191.0);
    float qx = pos[ni*2], qy = pos[ni*2+1];
    float s2 = qx*qx + qy*qy;
    int cx = min(max((int)(qx*(float)GDIM), 0), GDIM-1);
    int cy = min(max((int)(qy*(float)GDIM), 0), GDIM-1);
    const float h = 1.f/(float)GDIM;
    unsigned long long k0 = ~0ull, k1 = ~0ull, k2 = ~0ull;
    for (int rr = 0; rr < GDIM; ++rr) {
        if (rr > 0 && k2 != ~0ull) {
            float bound = rr*h;
            float d3 = __uint_as_float((unsigned)(k2 >> 32));
            if (d3 < bound*bound*0.9999f) break;
        }
        int ylo = max(cy-rr, 0), yhi = min(cy+rr, GDIM-1);
        int xlo = max(cx-rr, 0), xhi = min(cx+rr, GDIM-1);
        for (int gy = ylo; gy <= yhi; ++gy) {
            bool yedge = (gy == cy-rr) || (gy == cy+rr);
            for (int gx = xlo; gx <= xhi; ++gx) {
                if (!yedge && gx != cx-rr && gx != cx+rr) continue;
                int cell = gy*GDIM + gx;
                int s = gstart[cell], e = gstart[cell+1];
                for (; s < e; ++s) {
                    float2 p = psort[s];
                    float sc = p.x*p.x + p.y*p.y;
                    float dt = qx*p.x + qy*p.y;
                    float d2 = fmaxf(s2 + sc - 2.f*dt, 0.f);
                    unsigned long long key =
                        ((unsigned long long)__float_as_uint(d2) << 32) | (unsigned)pidx[s];
                    unsigned long long a0 = umin64(k0, key);
                    unsigned long long a1 = umin64(k1, umax64(k0, key));
                    unsigned long long a2 = umin64(k2, umax64(k1, key));
                    k0 = a0; k1 = a1; k2 = a2;
                }
            }
        }
    }
    float d0 = __uint_as_float((unsigned)(k0 >> 32));
    float d1 = __uint_as_float((unsigned)(k1 >> 32));
    float d2 = __uint_as_float((unsigned)(k2 >> 32));
    float w0 = 1.f/(sqrtf(d0) + 1e-8f);
    float w1 = 1.f/(sqrtf(d1) + 1e-8f);
    float w2 = 1.f/(sqrtf(d2) + 1e-8f);
    float ws = w0 + w1 + w2;
    atomicAdd(&coef[(int)(unsigned)(k0 & 0xffffffffu)], w0/ws);
    atomicAdd(&coef[(int)(unsigned)(k1 & 0xffffffffu)], w1/ws);
    atomicAdd(&coef[(int)(unsigned)(k2 & 0xffffffffu)], w2/ws);
}

// ---------------------------------------------------------------- layer-0 h aggregation (XCD-swizzled)
__global__ __launch_bounds__(256) void k_hagg0(
    const unsigned short* __restrict__ RT, const unsigned short* __restrict__ CT,
    const float* __restrict__ ef,
    const int* __restrict__ row, const int* __restrict__ col,
    const int* __restrict__ perm,
    const float* __restrict__ mW1e,
    float* __restrict__ agg)
{
    __shared__ float Ms[64][132];
    __shared__ float Pw[256];
    __shared__ float Es[64][2];
    __shared__ int colS[64], rowS[64], eS[64];
    int tid = threadIdx.x;
    int bid = blockIdx.x;
    int e0  = ((bid & 7)*512 + (bid >> 3)) * 64;   // XCD-contiguous tile ranges
    if (tid < 64) {
        int e = perm[e0 + tid];
        eS[tid] = e; colS[tid] = col[e]; rowS[tid] = row[e];
    }
    for (int t = tid; t < 256; t += 256) Pw[t] = mW1e[t];
    __syncthreads();
    if (tid < 128) { Es[tid>>1][tid&1] = ef[(size_t)eS[tid>>1]*2 + (tid&1)]; }
    __syncthreads();

    int mP = (tid >> 6)*16 + (tid & 15);
    int ccB = ((tid & 63) >> 4)*8;
    float e0v = Es[mP][0], e1v = Es[mP][1];
    const unsigned short* rbase = RT + (size_t)rowS[mP]*RCS + 128;
    const unsigned short* cbase = CT + (size_t)colS[mP]*RCS + 128;
    #pragma unroll
    for (int s4 = 0; s4 < 4; ++s4) {
        int cc = s4*32 + ccB;
        uint4 ra = *(const uint4*)(rbase + cc);
        uint4 cb = *(const uint4*)(cbase + cc);
        float rf[8], cf[8];
        unp8(ra, rf); unp8(cb, cf);
        float4 o0, o1;
        o0.x = fmaxf(rf[0]+cf[0]+e0v*Pw[cc+0]+e1v*Pw[128+cc+0], 0.f);
        o0.y = fmaxf(rf[1]+cf[1]+e0v*Pw[cc+1]+e1v*Pw[128+cc+1], 0.f);
        o0.z = fmaxf(rf[2]+cf[2]+e0v*Pw[cc+2]+e1v*Pw[128+cc+2], 0.f);
        o0.w = fmaxf(rf[3]+cf[3]+e0v*Pw[cc+3]+e1v*Pw[128+cc+3], 0.f);
        o1.x = fmaxf(rf[4]+cf[4]+e0v*Pw[cc+4]+e1v*Pw[128+cc+4], 0.f);
        o1.y = fmaxf(rf[5]+cf[5]+e0v*Pw[cc+5]+e1v*Pw[128+cc+5], 0.f);
        o1.z = fmaxf(rf[6]+cf[6]+e0v*Pw[cc+6]+e1v*Pw[128+cc+6], 0.f);
        o1.w = fmaxf(rf[7]+cf[7]+e0v*Pw[cc+7]+e1v*Pw[128+cc+7], 0.f);
        *(float4*)&Ms[mP][cc]   = o0;
        *(float4*)&Ms[mP][cc+4] = o1;
    }
    __syncthreads();

    {
        int n = tid & 127, hh = tid >> 7;
        int m0 = hh*32;
        float accv = 0.f;
        int cur = colS[m0];
        for (int m = m0; m < m0 + 32; ++m) {
            int cm = colS[m];
            if (cm != cur) {
                atomicAdd(&agg[(size_t)cur*HD + n], accv);
                accv = 0.f; cur = cm;
            }
            accv += Ms[m][n];
        }
        atomicAdd(&agg[(size_t)cur*HD + n], accv);
    }
}

union MsHFu { uint4 HF4[1024]; float Ms[64][132]; };

// ---------------------------------------------------------------- FUSED edge(l) + msg(l+1), XCD-swizzled, combined tables
__global__ __launch_bounds__(256) void k_edgemsg2(
    const unsigned short* __restrict__ RT, const unsigned short* __restrict__ CT,
    float* __restrict__ ef,
    const int* __restrict__ row, const int* __restrict__ col,
    const int* __restrict__ perm,
    const float* __restrict__ eW1e,
    const unsigned short* __restrict__ eW2p, const float* __restrict__ eB2,
    const float* __restrict__ elg, const float* __restrict__ elb,
    const float* __restrict__ mW1e,
    float* __restrict__ agg, int writeEf)
{
    __shared__ MsHFu MU;
    __shared__ float Pew[256], Pmw[256];
    __shared__ float Es[64][2];
    __shared__ int colS[64], rowS[64], eS[64];
    int tid = threadIdx.x;
    int bid = blockIdx.x;
    int e0  = ((bid & 7)*512 + (bid >> 3)) * 64;   // XCD-contiguous tile ranges
    if (tid < 64) {
        int e = perm[e0 + tid];
        eS[tid] = e; colS[tid] = col[e]; rowS[tid] = row[e];
    }
    for (int t = tid; t < 256; t += 256) { Pew[t] = eW1e[t]; Pmw[t] = mW1e[t]; }
    __syncthreads();

    int mP = (tid >> 6)*16 + (tid & 15);
    int ccB = ((tid & 63) >> 4)*8;
    const unsigned short* rbase = RT + (size_t)rowS[mP]*RCS;
    const unsigned short* cbase = CT + (size_t)colS[mP]*RCS;
    // prefetch msg-phase gathers (high half of combined rows) — hide behind edge phase
    uint4 regR[4], regC[4];
    #pragma unroll
    for (int s4 = 0; s4 < 4; ++s4) {
        int cc = s4*32 + ccB;
        regR[s4] = *(const uint4*)(rbase + 128 + cc);
        regC[s4] = *(const uint4*)(cbase + 128 + cc);
    }
    if (tid < 128) { Es[tid>>1][tid&1] = ef[(size_t)eS[tid>>1]*2 + (tid&1)]; }
    __syncthreads();

    int lane = tid & 63, wave = tid >> 6;
    int lr = lane & 15, lq = lane >> 4;

    // ---- edge phase: build He (bf16, fragment-major) from low halves
    {
        float e0v = Es[mP][0], e1v = Es[mP][1];
        #pragma unroll
        for (int s4 = 0; s4 < 4; ++s4) {
            int s = tid + s4*256;
            int cc = s4*32 + ccB;
            uint4 ra = *(const uint4*)(rbase + cc);
            uint4 cb = *(const uint4*)(cbase + cc);
            float rf[8], cf[8];
            unp8(ra, rf); unp8(cb, cf);
            unsigned short hb[8];
            #pragma unroll
            for (int j = 0; j < 8; ++j) {
                int n = cc + j;
                float o = rf[j] + cf[j] + e0v*Pew[n] + e1v*Pew[128+n];
                hb[j] = f2bf(fmaxf(o, 0.f));
            }
            uint4 pk;
            pk.x = hb[0] | ((unsigned)hb[1]<<16); pk.y = hb[2] | ((unsigned)hb[3]<<16);
            pk.z = hb[4] | ((unsigned)hb[5]<<16); pk.w = hb[6] | ((unsigned)hb[7]<<16);
            MU.HF4[s] = pk;
        }
    }
    __syncthreads();

    // edge stage-2: per-wave 16 edges, 16-col zero-padded tile
    f32x4 a2 = (f32x4){0.f,0.f,0.f,0.f};
    for (int ks = 0; ks < 4; ++ks) {
        short8 a = *(const short8*)&MU.HF4[(ks*4 + wave)*64 + lane];
        short8 b = *(const short8*)(eW2p + (size_t)(ks*64 + lane)*8);
        a2 = __builtin_amdgcn_mfma_f32_16x16x32_bf16(a, b, a2, 0,0,0);
    }
    if (lr < 2) {
        int d = lr;
        float bb = eB2[d];
        float gg = elg[d], bl = elb[d];
        #pragma unroll
        for (int r = 0; r < 4; ++r) {
            int m = wave*16 + lq*4 + r;
            float rv = Es[m][d] + a2[r] + bb;
            float other = __shfl_xor(rv, 1, 64);
            float mm = 0.5f*(rv + other);
            float dr = rv - mm, dro = other - mm;
            float vv = 0.5f*(dr*dr + dro*dro);
            float outv = dr / sqrtf(vv + 1e-5f) * gg + bl;
            Es[m][d] = outv;
            if (writeEf) ef[(size_t)eS[m]*2 + d] = outv;
        }
    }
    __syncthreads();

    // ---- msg phase from prefetched high halves + NEW ef
    {
        float e0v = Es[mP][0], e1v = Es[mP][1];
        #pragma unroll
        for (int s4 = 0; s4 < 4; ++s4) {
            int cc = s4*32 + ccB;
            float rf[8], cf[8];
            unp8(regR[s4], rf); unp8(regC[s4], cf);
            float4 o0, o1;
            o0.x = fmaxf(rf[0]+cf[0]+e0v*Pmw[cc+0]+e1v*Pmw[128+cc+0], 0.f);
            o0.y = fmaxf(rf[1]+cf[1]+e0v*Pmw[cc+1]+e1v*Pmw[128+cc+1], 0.f);
            o0.z = fmaxf(rf[2]+cf[2]+e0v*Pmw[cc+2]+e1v*Pmw[128+cc+2], 0.f);
            o0.w = fmaxf(rf[3]+cf[3]+e0v*Pmw[cc+3]+e1v*Pmw[128+cc+3], 0.f);
            o1.x = fmaxf(rf[4]+cf[4]+e0v*Pmw[cc+4]+e1v*Pmw[128+cc+4], 0.f);
            o1.y = fmaxf(rf[5]+cf[5]+e0v*Pmw[cc+5]+e1v*Pmw[128+cc+5], 0.f);
            o1.z = fmaxf(rf[6]+cf[6]+e0v*Pmw[cc+6]+e1v*Pmw[128+cc+6], 0.f);
            o1.w = fmaxf(rf[7]+cf[7]+e0v*Pmw[cc+7]+e1v*Pmw[128+cc+7], 0.f);
            *(float4*)&MU.Ms[mP][cc]   = o0;
            *(float4*)&MU.Ms[mP][cc+4] = o1;
        }
    }
    __syncthreads();

    {
        int n = tid & 127, hh = tid >> 7;
        int m0 = hh*32;
        float accv = 0.f;
        int cur = colS[m0];
        for (int m = m0; m < m0 + 32; ++m) {
            int cm = colS[m];
            if (cm != cur) {
                atomicAdd(&agg[(size_t)cur*HD + n], accv);
                accv = 0.f; cur = cm;
            }
            accv += MU.Ms[m][n];
        }
        atomicAdd(&agg[(size_t)cur*HD + n], accv);
    }
}

// ---------------------------------------------------------------- node update
union XRu { unsigned short Xs[64][264]; float Rs[64][132]; };

__global__ __launch_bounds__(256) void k_node_mfma(
    float* __restrict__ u, unsigned short* __restrict__ u16,
    float* __restrict__ agg, const int* __restrict__ cnt,
    const unsigned short* __restrict__ W1p, const float* __restrict__ B1,
    const unsigned short* __restrict__ W2p, const float* __restrict__ B2,
    const float* __restrict__ lg, const float* __restrict__ lb,
    const unsigned short* __restrict__ mW2pC, const float* __restrict__ mB2C,
    int doExtra,
    const unsigned short* __restrict__ eW1p, const float* __restrict__ eB1c,
    const unsigned short* __restrict__ mW1pN, const float* __restrict__ mB1N,
    unsigned short* __restrict__ RT, unsigned short* __restrict__ CT)
{
    __shared__ XRu XR;
    __shared__ HUu HU;
    __shared__ float red[64][4];
    __shared__ float mstat[64], sstat[64];
    __shared__ float invS[64], fS[64];
    int tid = threadIdx.x;
    int n0  = blockIdx.x * 64;
    for (int t = tid; t < 1024; t += 256) {
        int el = t >> 4, kc = t & 15;
        uint4 v = *(const uint4*)(u16 + (size_t)(n0+el)*HD + kc*8);
        *(uint4*)&XR.Xs[el][kc*8] = v;
    }
    if (tid < 64) {
        int c = cnt[n0 + tid];
        invS[tid] = 1.f / fmaxf((float)c, 1.f);
        fS[tid] = (c > 0) ? 1.f : 0.f;
    }
    for (int t = tid; t < 1024; t += 256) {
        int lane_s = t & 63, ksmt = t >> 6;
        int ks = ksmt >> 2, mt = ksmt & 3;
        int el = mt*16 + (lane_s & 15);
        int cc = ks*32 + (lane_s >> 4)*8;
        const float* src = agg + (size_t)(n0+el)*HD + cc;
        float4 a = *(const float4*)src;
        float4 b = *(const float4*)(src + 4);
        uint4 pk;
        pk.x = f2bf(a.x) | ((unsigned)f2bf(a.y) << 16);
        pk.y = f2bf(a.z) | ((unsigned)f2bf(a.w) << 16);
        pk.z = f2bf(b.x) | ((unsigned)f2bf(b.y) << 16);
        pk.w = f2bf(b.z) | ((unsigned)f2bf(b.w) << 16);
        HU.UF4[t] = pk;
    }
    __syncthreads();

    int lane = tid & 63, wave = tid >> 6;
    int lr = lane & 15, lq = lane >> 4;
    f32x4 acc[8];

    #pragma unroll
    for (int i = 0; i < 8; ++i) acc[i] = (f32x4){0.f,0.f,0.f,0.f};
    for (int ks = 0; ks < 4; ++ks) {
        short8 a0 = *(const short8*)&HU.UF4[(ks*4+0)*64 + lane];
        short8 a1 = *(const short8*)&HU.UF4[(ks*4+1)*64 + lane];
        short8 a2 = *(const short8*)&HU.UF4[(ks*4+2)*64 + lane];
        short8 a3 = *(const short8*)&HU.UF4[(ks*4+3)*64 + lane];
        short8 b0 = *(const short8*)(mW2pC + (size_t)(((wave*2+0)*4 + ks)*64 + lane)*8);
        short8 b1 = *(const short8*)(mW2pC + (size_t)(((wave*2+1)*4 + ks)*64 + lane)*8);
        acc[0] = __builtin_amdgcn_mfma_f32_16x16x32_bf16(a0, b0, acc[0], 0,0,0);
        acc[1] = __builtin_amdgcn_mfma_f32_16x16x32_bf16(a0, b1, acc[1], 0,0,0);
        acc[2] = __builtin_amdgcn_mfma_f32_16x16x32_bf16(a1, b0, acc[2], 0,0,0);
        acc[3] = __builtin_amdgcn_mfma_f32_16x16x32_bf16(a1, b1, acc[3], 0,0,0);
        acc[4] = __builtin_amdgcn_mfma_f32_16x16x32_bf16(a2, b0, acc[4], 0,0,0);
        acc[5] = __builtin_amdgcn_mfma_f32_16x16x32_bf16(a2, b1, acc[5], 0,0,0);
        acc[6] = __builtin_amdgcn_mfma_f32_16x16x32_bf16(a3, b0, acc[6], 0,0,0);
        acc[7] = __builtin_amdgcn_mfma_f32_16x16x32_bf16(a3, b1, acc[7], 0,0,0);
    }
    #pragma unroll
    for (int b = 0; b < 2; ++b) {
        int n = (wave*2 + b)*16 + lr;
        float bb = mB2C[n];
        #pragma unroll
        for (int mt = 0; mt < 4; ++mt) {
            f32x4 v = acc[mt*2 + b];
            #pragma unroll
            for (int r = 0; r < 4; ++r) {
                int m = mt*16 + lq*4 + r;
                float val = v[r]*invS[m] + fS[m]*bb;
                unsigned hv = f2bf(val);
                unsigned ph = (unsigned)__shfl_xor((int)hv, 1, 64);
                if (!(lr & 1))
                    *(unsigned*)&XR.Xs[m][128 + n] = hv | (ph << 16);
            }
        }
    }
    __syncthreads();

    #pragma unroll
    for (int i = 0; i < 8; ++i) acc[i] = (f32x4){0.f,0.f,0.f,0.f};
    for (int ks = 0; ks < 8; ++ks) {
        short8 a0 = *(const short8*)&XR.Xs[ 0 + lr][ks*32 + lq*8];
        short8 a1 = *(const short8*)&XR.Xs[16 + lr][ks*32 + lq*8];
        short8 a2 = *(const short8*)&XR.Xs[32 + lr][ks*32 + lq*8];
        short8 a3 = *(const short8*)&XR.Xs[48 + lr][ks*32 + lq*8];
        short8 b0 = *(const short8*)(W1p + (size_t)(((wave*2+0)*8 + ks)*64 + lane)*8);
        short8 b1 = *(const short8*)(W1p + (size_t)(((wave*2+1)*8 + ks)*64 + lane)*8);
        acc[0] = __builtin_amdgcn_mfma_f32_16x16x32_bf16(a0, b0, acc[0], 0,0,0);
        acc[1] = __builtin_amdgcn_mfma_f32_16x16x32_bf16(a0, b1, acc[1], 0,0,0);
        acc[2] = __builtin_amdgcn_mfma_f32_16x16x32_bf16(a1, b0, acc[2], 0,0,0);
        acc[3] = __builtin_amdgcn_mfma_f32_16x16x32_bf16(a1, b1, acc[3], 0,0,0);
        acc[4] = __builtin_amdgcn_mfma_f32_16x16x32_bf16(a2, b0, acc[4], 0,0,0);
        acc[5] = __builtin_amdgcn_mfma_f32_16x16x32_bf16(a2, b1, acc[5], 0,0,0);
        acc[6] = __builtin_amdgcn_mfma_f32_16x16x32_bf16(a3, b0, acc[6], 0,0,0);
        acc[7] = __builtin_amdgcn_mfma_f32_16x16x32_bf16(a3, b1, acc[7], 0,0,0);
    }
    #pragma unroll
    for (int b = 0; b < 2; ++b) {
        int n = (wave*2 + b)*16 + lr;
        float bb = B1[n];
        #pragma unroll
        for (int mt = 0; mt < 4; ++mt) {
            f32x4 v = acc[mt*2 + b];
            #pragma unroll
            for (int r = 0; r < 4; ++r) {
                int m = mt*16 + lq*4 + r;
                HU.Hs[m][n] = f2bf(fmaxf(v[r] + bb, 0.f));
            }
        }
    }
    __syncthreads();

    #pragma unroll
    for (int i = 0; i < 8; ++i) acc[i] = (f32x4){0.f,0.f,0.f,0.f};
    for (int ks = 0; ks < 4; ++ks) {
        short8 a0 = *(const short8*)&HU.Hs[ 0 + lr][ks*32 + lq*8];
        short8 a1 = *(const short8*)&HU.Hs[16 + lr][ks*32 + lq*8];
        short8 a2 = *(const short8*)&HU.Hs[32 + lr][ks*32 + lq*8];
        short8 a3 = *(const short8*)&HU.Hs[48 + lr][ks*32 + lq*8];
        short8 b0 = *(const short8*)(W2p + (size_t)(((wave*2+0)*4 + ks)*64 + lane)*8);
        short8 b1 = *(const short8*)(W2p + (size_t)(((wave*2+1)*4 + ks)*64 + lane)*8);
        acc[0] = __builtin_amdgcn_mfma_f32_16x16x32_bf16(a0, b0, acc[0], 0,0,0);
        acc[1] = __builtin_amdgcn_mfma_f32_16x16x32_bf16(a0, b1, acc[1], 0,0,0);
        acc[2] = __builtin_amdgcn_mfma_f32_16x16x32_bf16(a1, b0, acc[2], 0,0,0);
        acc[3] = __builtin_amdgcn_mfma_f32_16x16x32_bf16(a1, b1, acc[3], 0,0,0);
        acc[4] = __builtin_amdgcn_mfma_f32_16x16x32_bf16(a2, b0, acc[4], 0,0,0);
        acc[5] = __builtin_amdgcn_mfma_f32_16x16x32_bf16(a2, b1, acc[5], 0,0,0);
        acc[6] = __builtin_amdgcn_mfma_f32_16x16x32_bf16(a3, b0, acc[6], 0,0,0);
        acc[7] = __builtin_amdgcn_mfma_f32_16x16x32_bf16(a3, b1, acc[7], 0,0,0);
    }
    #pragma unroll
    for (int b = 0; b < 2; ++b) {
        int n = (wave*2 + b)*16 + lr;
        float bb = B2[n];
        #pragma unroll
        for (int mt = 0; mt < 4; ++mt) {
            f32x4 v = acc[mt*2 + b];
            #pragma unroll
            for (int r = 0; r < 4; ++r) {
                int m = mt*16 + lq*4 + r;
                XR.Rs[m][n] = u[(size_t)(n0+m)*HD + n] + v[r] + bb;
            }
        }
    }
    __syncthreads();
    {
        int m = tid >> 2, p = tid & 3;
        float s = 0.f;
        #pragma unroll 8
        for (int i = 0; i < 32; ++i) s += XR.Rs[m][p*32 + i];
        red[m][p] = s;
    }
    __syncthreads();
    if (tid < 64) mstat[tid] = (red[tid][0]+red[tid][1]+red[tid][2]+red[tid][3]) * (1.f/HD);
    __syncthreads();
    {
        int m = tid >> 2, p = tid & 3;
        float mm = mstat[m];
        float s = 0.f;
        #pragma unroll 8
        for (int i = 0; i < 32; ++i) { float d = XR.Rs[m][p*32 + i] - mm; s += d*d; }
        red[m][p] = s;
    }
    __syncthreads();
    if (tid < 64) sstat[tid] = sqrtf((red[tid][0]+red[tid][1]+red[tid][2]+red[tid][3]) * (1.f/HD) + 1e-5f);
    __syncthreads();
    for (int t = tid; t < 2048; t += 256) {
        int m = t >> 5, q = t & 31;
        int n = q*4;
        float mm = mstat[m], sd = sstat[m];
        float4 g4 = *(const float4*)(lg + n);
        float4 b4 = *(const float4*)(lb + n);
        float o0 = (XR.Rs[m][n+0]-mm)/sd*g4.x + b4.x;
        float o1 = (XR.Rs[m][n+1]-mm)/sd*g4.y + b4.y;
        float o2 = (XR.Rs[m][n+2]-mm)/sd*g4.z + b4.z;
        float o3 = (XR.Rs[m][n+3]-mm)/sd*g4.w + b4.w;
        float4 fo; fo.x=o0; fo.y=o1; fo.z=o2; fo.w=o3;
        *(float4*)(u + (size_t)(n0+m)*HD + n) = fo;
        uint2 pk; pk.x = f2bf(o0) | (f2bf(o1)<<16); pk.y = f2bf(o2) | (f2bf(o3)<<16);
        *(uint2*)(u16 + (size_t)(n0+m)*HD + n) = pk;
        if (doExtra) {
            int ksf = n >> 5, sub = (n >> 3) & 3;
            int slot = (ksf*4 + (m >> 4))*64 + ((m & 15) | (sub << 4));
            unsigned short* UF = (unsigned short*)HU.UF4;
            *(uint2*)&UF[slot*8 + (n & 7)] = pk;
        }
    }
    {
        float4 z; z.x=0.f; z.y=0.f; z.z=0.f; z.w=0.f;
        for (int t = tid; t < 2048; t += 256)
            *(float4*)(agg + (size_t)(n0 + (t>>5))*HD + (t&31)*4) = z;
    }
    if (!doExtra) return;
    __syncthreads();

    // 4 GEMMs into combined tables: RT low (RE), CT low (CE+eB1), RT high (RM), CT high (CM+mB1)
    for (int g = 0; g < 4; ++g) {
        const unsigned short* Bp = (g < 2) ? eW1p : mW1pN;
        int ksOff = (g & 1) * 4;
        unsigned short* Out = ((g & 1) ? CT : RT) + ((g < 2) ? 0 : 128);
        const float* bias = (g == 1) ? eB1c : (g == 3) ? mB1N : (const float*)nullptr;
        #pragma unroll
        for (int i = 0; i < 8; ++i) acc[i] = (f32x4){0.f,0.f,0.f,0.f};
        for (int ks = 0; ks < 4; ++ks) {
            short8 a0 = *(const short8*)&HU.UF4[(ks*4+0)*64 + lane];
            short8 a1 = *(const short8*)&HU.UF4[(ks*4+1)*64 + lane];
            short8 a2 = *(const short8*)&HU.UF4[(ks*4+2)*64 + lane];
            short8 a3 = *(const short8*)&HU.UF4[(ks*4+3)*64 + lane];
            short8 b0 = *(const short8*)(Bp + (size_t)(((wave*2+0)*8 + ksOff + ks)*64 + lane)*8);
            short8 b1 = *(const short8*)(Bp + (size_t)(((wave*2+1)*8 + ksOff + ks)*64 + lane)*8);
            acc[0] = __builtin_amdgcn_mfma_f32_16x16x32_bf16(a0, b0, acc[0], 0,0,0);
            acc[1] = __builtin_amdgcn_mfma_f32_16x16x32_bf16(a0, b1, acc[1], 0,0,0);
            acc[2] = __builtin_amdgcn_mfma_f32_16x16x32_bf16(a1, b0, acc[2], 0,0,0);
            acc[3] = __builtin_amdgcn_mfma_f32_16x16x32_bf16(a1, b1, acc[3], 0,0,0);
            acc[4] = __builtin_amdgcn_mfma_f32_16x16x32_bf16(a2, b0, acc[4], 0,0,0);
            acc[5] = __builtin_amdgcn_mfma_f32_16x16x32_bf16(a2, b1, acc[5], 0,0,0);
            acc[6] = __builtin_amdgcn_mfma_f32_16x16x32_bf16(a3, b0, acc[6], 0,0,0);
            acc[7] = __builtin_amdgcn_mfma_f32_16x16x32_bf16(a3, b1, acc[7], 0,0,0);
        }
        #pragma unroll
        for (int b = 0; b < 2; ++b) {
            int n = (wave*2 + b)*16 + lr;
            float bb = bias ? bias[n] : 0.f;
            #pragma unroll
            for (int mt = 0; mt < 4; ++mt) {
                f32x4 v = acc[mt*2 + b];
                #pragma unroll
                for (int r = 0; r < 4; ++r) {
                    int rowp = n0 + mt*16 + lq*4 + r;
                    unsigned hv = f2bf(v[r] + bb);
                    unsigned ph = (unsigned)__shfl_xor((int)hv, 1, 64);
                    if (!(lr & 1))
                        *(unsigned*)&Out[(size_t)rowp*RCS + n] = hv | (ph << 16);
                }
            }
        }
    }
}

// ---------------------------------------------------------------- stage 4+5: u3 = LN(MLP(u)), fused coef-weighted pool -> partial
__global__ __launch_bounds__(256) void k_m2_mfma(
    const unsigned short* __restrict__ u16,
    const unsigned short* __restrict__ W1p, const float* __restrict__ B1,
    const unsigned short* __restrict__ W2p, const float* __restrict__ B2,
    const float* __restrict__ lg, const float* __restrict__ lb,
    const float* __restrict__ coef, float* __restrict__ partial)
{
    __shared__ unsigned short Xs[64][136];
    __shared__ unsigned short Hs[64][136];
    __shared__ float Rs[64][132];
    __shared__ float red[64][4];
    __shared__ float mstat[64], sstat[64];
    __shared__ float zp[HD];
    int tid = threadIdx.x;
    int n0  = blockIdx.x * 64;
    if (tid < HD) zp[tid] = 0.f;
    for (int t = tid; t < 1024; t += 256) {
        int el = t >> 4, kc = t & 15;
        uint4 v = *(const uint4*)(u16 + (size_t)(n0+el)*HD + kc*8);
        *(uint4*)&Xs[el][kc*8] = v;
    }
    __syncthreads();

    int lane = tid & 63, wave = tid >> 6;
    int lr = lane & 15, lq = lane >> 4;
    f32x4 acc[8];
    #pragma unroll
    for (int i = 0; i < 8; ++i) acc[i] = (f32x4){0.f,0.f,0.f,0.f};
    for (int ks = 0; ks < 4; ++ks) {
        short8 a0 = *(const short8*)&Xs[ 0 + lr][ks*32 + lq*8];
        short8 a1 = *(const short8*)&Xs[16 + lr][ks*32 + lq*8];
        short8 a2 = *(const short8*)&Xs[32 + lr][ks*32 + lq*8];
        short8 a3 = *(const short8*)&Xs[48 + lr][ks*32 + lq*8];
        short8 b0 = *(const short8*)(W1p + (size_t)(((wave*2+0)*4 + ks)*64 + lane)*8);
        short8 b1 = *(const short8*)(W1p + (size_t)(((wave*2+1)*4 + ks)*64 + lane)*8);
        acc[0] = __builtin_amdgcn_mfma_f32_16x16x32_bf16(a0, b0, acc[0], 0,0,0);
        acc[1] = __builtin_amdgcn_mfma_f32_16x16x32_bf16(a0, b1, acc[1], 0,0,0);
        acc[2] = __builtin_amdgcn_mfma_f32_16x16x32_bf16(a1, b0, acc[2], 0,0,0);
        acc[3] = __builtin_amdgcn_mfma_f32_16x16x32_bf16(a1, b1, acc[3], 0,0,0);
        acc[4] = __builtin_amdgcn_mfma_f32_16x16x32_bf16(a2, b0, acc[4], 0,0,0);
        acc[5] = __builtin_amdgcn_mfma_f32_16x16x32_bf16(a2, b1, acc[5], 0,0,0);
        acc[6] = __builtin_amdgcn_mfma_f32_16x16x32_bf16(a3, b0, acc[6], 0,0,0);
        acc[7] = __builtin_amdgcn_mfma_f32_16x16x32_bf16(a3, b1, acc[7], 0,0,0);
    }
    #pragma unroll
    for (int b = 0; b < 2; ++b) {
        int n = (wave*2 + b)*16 + lr;
        float bb = B1[n];
        #pragma unroll
        for (int mt = 0; mt < 4; ++mt) {
            f32x4 v = acc[mt*2 + b];
            #pragma unroll
            for (int r = 0; r < 4; ++r) {
                int m = mt*16 + lq*4 + r;
                Hs[m][n] = f2bf(fmaxf(v[r] + bb, 0.f));
            }
        }
    }
    __syncthreads();

    #pragma unroll
    for (int i = 0; i < 8; ++i) acc[i] = (f32x4){0.f,0.f,0.f,0.f};
    for (int ks = 0; ks < 4; ++ks) {
        short8 a0 = *(const short8*)&Hs[ 0 + lr][ks*32 + lq*8];
        short8 a1 = *(const short8*)&Hs[16 + lr][ks*32 + lq*8];
        short8 a2 = *(const short8*)&Hs[32 + lr][ks*32 + lq*8];
        short8 a3 = *(const short8*)&Hs[48 + lr][ks*32 + lq*8];
        short8 b0 = *(const short8*)(W2p + (size_t)(((wave*2+0)*4 + ks)*64 + lane)*8);
        short8 b1 = *(const short8*)(W2p + (size_t)(((wave*2+1)*4 + ks)*64 + lane)*8);
        acc[0] = __builtin_amdgcn_mfma_f32_16x16x32_bf16(a0, b0, acc[0], 0,0,0);
        acc[1] = __builtin_amdgcn_mfma_f32_16x16x32_bf16(a0, b1, acc[1], 0,0,0);
        acc[2] = __builtin_amdgcn_mfma_f32_16x16x32_bf16(a1, b0, acc[2], 0,0,0);
        acc[3] = __builtin_amdgcn_mfma_f32_16x16x32_bf16(a1, b1, acc[3], 0,0,0);
        acc[4] = __builtin_amdgcn_mfma_f32_16x16x32_bf16(a2, b0, acc[4], 0,0,0);
        acc[5] = __builtin_amdgcn_mfma_f32_16x16x32_bf16(a2, b1, acc[5], 0,0,0);
        acc[6] = __builtin_amdgcn_mfma_f32_16x16x32_bf16(a3, b0, acc[6], 0,0,0);
        acc[7] = __builtin_amdgcn_mfma_f32_16x16x32_bf16(a3, b1, acc[7], 0,0,0);
    }
    #pragma unroll
    for (int b = 0; b < 2; ++b) {
        int n = (wave*2 + b)*16 + lr;
        float bb = B2[n];
        #pragma unroll
        for (int mt = 0; mt < 4; ++mt) {
            f32x4 v = acc[mt*2 + b];
            #pragma unroll
            for (int r = 0; r < 4; ++r) {
                int m = mt*16 + lq*4 + r;
                Rs[m][n] = v[r] + bb;
            }
        }
    }
    __syncthreads();
    {
        int m = tid >> 2, p = tid & 3;
        float s = 0.f;
        #pragma unroll 8
        for (int i = 0; i < 32; ++i) s += Rs[m][p*32 + i];
        red[m][p] = s;
    }
    __syncthreads();
    if (tid < 64) mstat[tid] = (red[tid][0]+red[tid][1]+red[tid][2]+red[tid][3]) * (1.f/HD);
    __syncthreads();
    {
        int m = tid >> 2, p = tid & 3;
        float mm = mstat[m];
        float s = 0.f;
        #pragma unroll 8
        for (int i = 0; i < 32; ++i) { float d = Rs[m][p*32 + i] - mm; s += d*d; }
        red[m][p] = s;
    }
    __syncthreads();
    if (tid < 64) sstat[tid] = sqrtf((red[tid][0]+red[tid][1]+red[tid][2]+red[tid][3]) * (1.f/HD) + 1e-5f);
    __syncthreads();
    {
        float4 a4; a4.x=0.f; a4.y=0.f; a4.z=0.f; a4.w=0.f;
        int q = tid & 31;
        int n = q*4;
        float4 g4 = *(const float4*)(lg + n);
        float4 b4 = *(const float4*)(lb + n);
        for (int t = tid; t < 2048; t += 256) {
            int m = t >> 5;
            float mm = mstat[m], sd = sstat[m];
            float cw = coef[n0 + m];
            float o0 = (Rs[m][n+0]-mm)/sd*g4.x + b4.x;
            float o1 = (Rs[m][n+1]-mm)/sd*g4.y + b4.y;
            float o2 = (Rs[m][n+2]-mm)/sd*g4.z + b4.z;
            float o3 = (Rs[m][n+3]-mm)/sd*g4.w + b4.w;
            a4.x += cw*o0; a4.y += cw*o1; a4.z += cw*o2; a4.w += cw*o3;
        }
        atomicAdd(&zp[n+0], a4.x);
        atomicAdd(&zp[n+1], a4.y);
        atomicAdd(&zp[n+2], a4.z);
        atomicAdd(&zp[n+3], a4.w);
    }
    __syncthreads();
    if (tid < HD) partial[(size_t)blockIdx.x*HD + tid] = zp[tid];
}

// ---------------------------------------------------------------- stage 6: reduce partials + output MLP
__global__ __launch_bounds__(128) void k_out(
    const float* __restrict__ partial,
    const float* __restrict__ w1, const float* __restrict__ b1,
    const float* __restrict__ w2, const float* __restrict__ b2,
    float* __restrict__ out)
{
    __shared__ float zs[HD];
    __shared__ float hs[HD];
    int j = threadIdx.x;
    float s = 0.f;
    for (int p = 0; p < NN/64; ++p) s += partial[(size_t)p*HD + j];
    zs[j] = s * (1.f/NRED);
    __syncthreads();
    float o = b1[j];
    #pragma unroll 8
    for (int k = 0; k < HD; ++k) o += zs[k]*w1[k*HD + j];
    hs[j] = fmaxf(o, 0.f);
    __syncthreads();
    if (j < LATD) {
        float o2 = b2[j];
        #pragma unroll 8
        for (int k = 0; k < HD; ++k) o2 += hs[k]*w2[k*LATD + j];
        out[j] = o2;
    }
}

extern "C" void kernel_launch(void* const* d_in, const int* in_sizes, int n_in,
                              void* d_out, int out_size, void* d_ws, size_t ws_size,
                              hipStream_t stream)
{
    const float* x    = (const float*)d_in[0];
    const float* pos  = (const float*)d_in[1];
    const int*   eidx = (const int*)d_in[2];
    const int* row = eidx;
    const int* col = eidx + NEDGE;
    const float* m0_w1 = (const float*)d_in[3];
    const float* m0_b1 = (const float*)d_in[4];
    const float* m0_w2 = (const float*)d_in[5];
    const float* m0_b2 = (const float*)d_in[6];
    const float* ln0_g = (const float*)d_in[7];
    const float* ln0_b = (const float*)d_in[8];
    const float* m1_w1 = (const float*)d_in[9];
    const float* m1_b1 = (const float*)d_in[10];
    const float* m1_w2 = (const float*)d_in[11];
    const float* m1_b2 = (const float*)d_in[12];
    const float* ln1_g = (const float*)d_in[13];
    const float* ln1_b = (const float*)d_in[14];
    const float* g_msg_w1  = (const float*)d_in[15];
    const float* g_msg_b1  = (const float*)d_in[16];
    const float* g_msg_w2  = (const float*)d_in[17];
    const float* g_msg_b2  = (const float*)d_in[18];
    const float* g_node_w1 = (const float*)d_in[19];
    const float* g_node_b1 = (const float*)d_in[20];
    const float* g_node_w2 = (const float*)d_in[21];
    const float* g_node_b2 = (const float*)d_in[22];
    const float* g_edge_w1 = (const float*)d_in[23];
    const float* g_edge_b1 = (const float*)d_in[24];
    const float* g_edge_w2 = (const float*)d_in[25];
    const float* g_edge_b2 = (const float*)d_in[26];
    const float* g_lnn_g   = (const float*)d_in[27];
    const float* g_lnn_b   = (const float*)d_in[28];
    const float* g_lne_g   = (const float*)d_in[29];
    const float* g_lne_b   = (const float*)d_in[30];
    const float* m2_w1 = (const float*)d_in[31];
    const float* m2_b1 = (const float*)d_in[32];
    const float* m2_w2 = (const float*)d_in[33];
    const float* m2_b2 = (const float*)d_in[34];
    const float* ln2_g = (const float*)d_in[35];
    const float* ln2_b = (const float*)d_in[36];
    const float* op_w1 = (const float*)d_in[37];
    const float* op_b1 = (const float*)d_in[38];
    const float* op_w2 = (const float*)d_in[39];
    const float* op_b2 = (const float*)d_in[40];

    float* u    = (float*)d_ws;                       // NN*HD f32
    float* ef   = u + (size_t)NN*HD;                  // NEDGE*2
    float* agg  = ef + (size_t)NEDGE*2;               // NN*HD (h-sums)
    int*   cnt  = (int*)(agg + (size_t)NN*HD);        // NN
    int*   gcnt = cnt + NN;                           // 1024
    float* coef = (float*)(gcnt + 1024);              // NN
    int*   head = (int*)(coef + NN);                  // NN
    int*   perm = head + NN;                          // NEDGE
    float* partial = (float*)(perm + NEDGE);          // (NN/64)*HD
    int*   gstart = (int*)(partial + (NN/64)*HD);     // 1026
    int*   ghead  = gstart + 1026;                    // 1024
    int*   pidx   = ghead + 1024;                     // NN
    float2* psort = (float2*)(pidx + NN);             // NN float2
    unsigned short* u16 = (unsigned short*)(psort + NN);  // NN*HD bf16
    unsigned short* packs = u16 + (size_t)NN*HD;      // PK_TOTAL shorts
    unsigned short* msgW1p  = packs;
    unsigned short* msgW2p  = packs + 98304;
    unsigned short* edgeW1p = packs + 147456;
    unsigned short* nodeW1p = packs + 245760;
    unsigned short* nodeW2p = packs + 344064;
    unsigned short* edgeW2p = packs + 393216;
    unsigned short* m0w2p   = packs + 399360;
    unsigned short* m2w1p   = packs + 415744;
    unsigned short* m2w2p   = packs + 432128;
    unsigned short* RT = packs + PK_TOTAL;            // NN*RCS (combined RE|RM)
    unsigned short* CT = RT + (size_t)NN*RCS;         // NN*RCS (combined CE|CM)

    k_pack_all<<<(PK_TOTAL + 255)/256, 256, 0, stream>>>(
        g_msg_w1, g_msg_w2, g_edge_w1, g_node_w1, g_node_w2, g_edge_w2,
        m0_w2, m2_w1, m2_w2, packs);

    hipMemsetAsync(cnt, 0, (NN + 1024 + NN)*sizeof(int), stream);

    k_nenc_mfma<<<NN/64, 256, 0, stream>>>(x, m0_w1, m0_b1, m0w2p, m0_b2, ln0_g, ln0_b,
                                           msgW1p, g_msg_b1, u, u16, RT, CT, agg);
    k_edge_enc<<<NEDGE/256, 256, 0, stream>>>(pos, row, col, m1_w1, m1_b1, m1_w2, m1_b2,
                                              ln1_g, ln1_b, ef);

    k_count2<<<NEDGE/256, 256, 0, stream>>>(col, pos, cnt, gcnt);
    k_scan2<<<2, 256, 0, stream>>>(cnt, head, gcnt, gstart, ghead);
    k_scatter2<<<NEDGE/256, 256, 0, stream>>>(col, pos, head, perm, ghead, psort, pidx);
    k_knnsel<<<NRED/256, 256, 0, stream>>>(pos, gstart, psort, pidx, coef);

    // layer 0: h-aggregation (msg tables in RT/CT high halves)
    k_hagg0<<<NEDGE/64, 256, 0, stream>>>(RT, CT, ef, row, col, perm,
        g_msg_w1 + 256*HD, agg);
    k_node_mfma<<<NN/64, 256, 0, stream>>>(u, u16, agg, cnt,
        nodeW1p, g_node_b1, nodeW2p, g_node_b2, g_lnn_g, g_lnn_b,
        msgW2p, g_msg_b2,
        1, edgeW1p + 0*32768, g_edge_b1 + 0*HD, msgW1p + 1*32768, g_msg_b1 + 1*HD,
        RT, CT);

    // fused edge(l) + msg(l+1); edge(2) is dead code
    for (int l = 0; l < NLAYER-1; ++l) {
        k_edgemsg2<<<NEDGE/64, 256, 0, stream>>>(RT, CT, ef, row, col, perm,
            g_edge_w1 + (size_t)l*258*HD + 256*HD,
            edgeW2p + l*2048, g_edge_b2 + l*2, g_lne_g + l*2, g_lne_b + l*2,
            g_msg_w1 + (size_t)(l+1)*258*HD + 256*HD,
            agg, (l == 0) ? 1 : 0);
        int doExtra = (l == 0) ? 1 : 0;
        k_node_mfma<<<NN/64, 256, 0, stream>>>(u, u16, agg, cnt,
            nodeW1p + (l+1)*32768, g_node_b1 + (l+1)*HD,
            nodeW2p + (l+1)*16384, g_node_b2 + (l+1)*HD,
            g_lnn_g + (l+1)*HD, g_lnn_b + (l+1)*HD,
            msgW2p + (l+1)*16384, g_msg_b2 + (l+1)*HD,
            doExtra, edgeW1p + 1*32768, g_edge_b1 + 1*HD, msgW1p + 2*32768, g_msg_b1 + 2*HD,
            RT, CT);
    }

    k_m2_mfma<<<NN/64, 256, 0, stream>>>(u16, m2w1p, m2_b1, m2w2p, m2_b2, ln2_g, ln2_b,
                                         coef, partial);
    k_out<<<1, 128, 0, stream>>>(partial, op_w1, op_b1, op_w2, op_b2, (float*)d_out);
}

// Round 12
// 462.815 us; speedup vs baseline: 1.0007x; 1.0007x over previous
//
#include <hip/hip_runtime.h>
#include <cfloat>

#define NN     16384
#define NEDGE  262144
#define HD     128
#define NLAYER 3
#define NRED   8192
#define LATD   64
#define GDIM   32
#define RCS    256   // combined row/col table stride (shorts)

typedef __attribute__((ext_vector_type(8))) short short8;
typedef __attribute__((ext_vector_type(4))) float f32x4;

__device__ __forceinline__ unsigned short f2bf(float f) {
    union { float f; unsigned u; } v; v.f = f;
    unsigned u = v.u;
    unsigned r = u + 0x7fff + ((u >> 16) & 1);
    return (unsigned short)(r >> 16);
}
__device__ __forceinline__ void unp8(uint4 v, float* f) {
    unsigned w0=v.x, w1=v.y, w2=v.z, w3=v.w;
    f[0]=__uint_as_float(w0<<16); f[1]=__uint_as_float(w0&0xffff0000u);
    f[2]=__uint_as_float(w1<<16); f[3]=__uint_as_float(w1&0xffff0000u);
    f[4]=__uint_as_float(w2<<16); f[5]=__uint_as_float(w2&0xffff0000u);
    f[6]=__uint_as_float(w3<<16); f[7]=__uint_as_float(w3&0xffff0000u);
}
__device__ __forceinline__ unsigned long long umin64(unsigned long long a, unsigned long long b) {
    return a < b ? a : b;
}
__device__ __forceinline__ unsigned long long umax64(unsigned long long a, unsigned long long b) {
    return a < b ? b : a;
}

// ---------------------------------------------------------------- consolidated weight packing
__device__ __forceinline__ unsigned short pack_std(const float* W, int ksteps, int q) {
    int j    = q & 7;
    int lane = (q >> 3) & 63;
    int ks   = (q >> 9) % ksteps;
    int nt   = q / (ksteps * 512);
    int k = ks*32 + (lane >> 4)*8 + j;
    int n = nt*16 + (lane & 15);
    return f2bf(W[k*128 + n]);
}
__device__ __forceinline__ unsigned short pack_w2e(const float* W, int q) {
    int j    = q & 7;
    int lane = (q >> 3) & 63;
    int ks   = q >> 9;
    int k = ks*32 + (lane >> 4)*8 + j;
    int n = lane & 15;
    return (n < 2) ? f2bf(W[k*2 + n]) : (unsigned short)0;
}

#define PK_TOTAL 448512
__global__ __launch_bounds__(256) void k_pack_all(
    const float* __restrict__ msgw1, const float* __restrict__ msgw2,
    const float* __restrict__ edgew1, const float* __restrict__ nodew1,
    const float* __restrict__ nodew2, const float* __restrict__ edgew2,
    const float* __restrict__ m0w2, const float* __restrict__ m2w1,
    const float* __restrict__ m2w2, unsigned short* __restrict__ P)
{
    int p = blockIdx.x*256 + threadIdx.x;
    if (p >= PK_TOTAL) return;
    unsigned short v;
    if (p < 98304) {
        int l = p / 32768, q = p % 32768;
        v = pack_std(msgw1 + (size_t)l*258*128, 8, q);
    } else if (p < 147456) {
        int t = p - 98304; int l = t / 16384, q = t % 16384;
        v = pack_std(msgw2 + (size_t)l*16384, 4, q);
    } else if (p < 245760) {
        int t = p - 147456; int l = t / 32768, q = t % 32768;
        v = pack_std(edgew1 + (size_t)l*258*128, 8, q);
    } else if (p < 344064) {
        int t = p - 245760; int l = t / 32768, q = t % 32768;
        v = pack_std(nodew1 + (size_t)l*256*128, 8, q);
    } else if (p < 393216) {
        int t = p - 344064; int l = t / 16384, q = t % 16384;
        v = pack_std(nodew2 + (size_t)l*16384, 4, q);
    } else if (p < 399360) {
        int t = p - 393216; int l = t / 2048, q = t % 2048;
        v = pack_w2e(edgew2 + (size_t)l*256, q);
    } else if (p < 415744) {
        v = pack_std(m0w2, 4, p - 399360);
    } else if (p < 432128) {
        v = pack_std(m2w1, 4, p - 415744);
    } else {
        v = pack_std(m2w2, 4, p - 432128);
    }
    P[p] = v;
}

union HUu { unsigned short Hs[64][136]; uint4 UF4[1024]; };

// ---------------------------------------------------------------- stage 1: node encoder + msg-table precompute (RT/CT high half) + agg zero
__global__ __launch_bounds__(256) void k_nenc_mfma(
    const float* __restrict__ x,
    const float* __restrict__ w1, const float* __restrict__ b1,
    const unsigned short* __restrict__ W2p, const float* __restrict__ B2,
    const float* __restrict__ lg, const float* __restrict__ lb,
    const unsigned short* __restrict__ mW1p, const float* __restrict__ mB1,
    float* __restrict__ u, unsigned short* __restrict__ u16,
    unsigned short* __restrict__ RT, unsigned short* __restrict__ CT,
    float* __restrict__ agg)
{
    __shared__ float xs[64][4];
    __shared__ float w1s[3][128];
    __shared__ float b1s[128];
    __shared__ HUu HU;
    __shared__ float Rs[64][132];
    __shared__ float red[64][4];
    __shared__ float mstat[64], sstat[64];
    int tid = threadIdx.x;
    int n0  = blockIdx.x * 64;
    {
        float4 z; z.x=0.f; z.y=0.f; z.z=0.f; z.w=0.f;
        for (int t = tid; t < 2048; t += 256)
            *(float4*)(agg + (size_t)(n0 + (t>>5))*HD + (t&31)*4) = z;
    }
    for (int t = tid; t < 384; t += 256) w1s[t >> 7][t & 127] = w1[t];
    if (tid < 128) b1s[tid] = b1[tid];
    for (int t = tid; t < 192; t += 256) xs[t/3][t%3] = x[(size_t)n0*3 + t];
    __syncthreads();
    {
        int m = tid >> 2, p0 = (tid & 3) * 32;
        float x0 = xs[m][0], x1 = xs[m][1], x2 = xs[m][2];
        for (int j = p0; j < p0 + 32; j += 2) {
            float h0 = fmaxf(b1s[j]   + x0*w1s[0][j]   + x1*w1s[1][j]   + x2*w1s[2][j],   0.f);
            float h1 = fmaxf(b1s[j+1] + x0*w1s[0][j+1] + x1*w1s[1][j+1] + x2*w1s[2][j+1], 0.f);
            *(unsigned*)&HU.Hs[m][j] = f2bf(h0) | ((unsigned)f2bf(h1) << 16);
        }
    }
    __syncthreads();

    int lane = tid & 63, wave = tid >> 6;
    int lr = lane & 15, lq = lane >> 4;
    f32x4 acc[8];
    #pragma unroll
    for (int i = 0; i < 8; ++i) acc[i] = (f32x4){0.f,0.f,0.f,0.f};
    for (int ks = 0; ks < 4; ++ks) {
        short8 a0 = *(const short8*)&HU.Hs[ 0 + lr][ks*32 + lq*8];
        short8 a1 = *(const short8*)&HU.Hs[16 + lr][ks*32 + lq*8];
        short8 a2 = *(const short8*)&HU.Hs[32 + lr][ks*32 + lq*8];
        short8 a3 = *(const short8*)&HU.Hs[48 + lr][ks*32 + lq*8];
        short8 b0 = *(const short8*)(W2p + (size_t)(((wave*2+0)*4 + ks)*64 + lane)*8);
        short8 b1v= *(const short8*)(W2p + (size_t)(((wave*2+1)*4 + ks)*64 + lane)*8);
        acc[0] = __builtin_amdgcn_mfma_f32_16x16x32_bf16(a0, b0, acc[0], 0,0,0);
        acc[1] = __builtin_amdgcn_mfma_f32_16x16x32_bf16(a0, b1v, acc[1], 0,0,0);
        acc[2] = __builtin_amdgcn_mfma_f32_16x16x32_bf16(a1, b0, acc[2], 0,0,0);
        acc[3] = __builtin_amdgcn_mfma_f32_16x16x32_bf16(a1, b1v, acc[3], 0,0,0);
        acc[4] = __builtin_amdgcn_mfma_f32_16x16x32_bf16(a2, b0, acc[4], 0,0,0);
        acc[5] = __builtin_amdgcn_mfma_f32_16x16x32_bf16(a2, b1v, acc[5], 0,0,0);
        acc[6] = __builtin_amdgcn_mfma_f32_16x16x32_bf16(a3, b0, acc[6], 0,0,0);
        acc[7] = __builtin_amdgcn_mfma_f32_16x16x32_bf16(a3, b1v, acc[7], 0,0,0);
    }
    #pragma unroll
    for (int b = 0; b < 2; ++b) {
        int n = (wave*2 + b)*16 + lr;
        float bb = B2[n];
        #pragma unroll
        for (int mt = 0; mt < 4; ++mt) {
            f32x4 v = acc[mt*2 + b];
            #pragma unroll
            for (int r = 0; r < 4; ++r) {
                int m = mt*16 + lq*4 + r;
                Rs[m][n] = v[r] + bb;
            }
        }
    }
    __syncthreads();
    {
        int m = tid >> 2, p = tid & 3;
        float s = 0.f;
        #pragma unroll 8
        for (int i = 0; i < 32; ++i) s += Rs[m][p*32 + i];
        red[m][p] = s;
    }
    __syncthreads();
    if (tid < 64) mstat[tid] = (red[tid][0]+red[tid][1]+red[tid][2]+red[tid][3]) * (1.f/HD);
    __syncthreads();
    {
        int m = tid >> 2, p = tid & 3;
        float mm = mstat[m];
        float s = 0.f;
        #pragma unroll 8
        for (int i = 0; i < 32; ++i) { float d = Rs[m][p*32 + i] - mm; s += d*d; }
        red[m][p] = s;
    }
    __syncthreads();
    if (tid < 64) sstat[tid] = sqrtf((red[tid][0]+red[tid][1]+red[tid][2]+red[tid][3]) * (1.f/HD) + 1e-5f);
    __syncthreads();
    for (int t = tid; t < 2048; t += 256) {
        int m = t >> 5, q = t & 31;
        int n = q*4;
        float mm = mstat[m], sd = sstat[m];
        float4 g4 = *(const float4*)(lg + n);
        float4 b4 = *(const float4*)(lb + n);
        float o0 = (Rs[m][n+0]-mm)/sd*g4.x + b4.x;
        float o1 = (Rs[m][n+1]-mm)/sd*g4.y + b4.y;
        float o2 = (Rs[m][n+2]-mm)/sd*g4.z + b4.z;
        float o3 = (Rs[m][n+3]-mm)/sd*g4.w + b4.w;
        float4 fo; fo.x=o0; fo.y=o1; fo.z=o2; fo.w=o3;
        *(float4*)(u + (size_t)(n0+m)*HD + n) = fo;
        uint2 pk; pk.x = f2bf(o0) | (f2bf(o1)<<16); pk.y = f2bf(o2) | (f2bf(o3)<<16);
        *(uint2*)(u16 + (size_t)(n0+m)*HD + n) = pk;
        int ksf = n >> 5, sub = (n >> 3) & 3;
        int slot = (ksf*4 + (m >> 4))*64 + ((m & 15) | (sub << 4));
        unsigned short* UF = (unsigned short*)HU.UF4;
        *(uint2*)&UF[slot*8 + (n & 7)] = pk;
    }
    __syncthreads();

    // msg tables: RT[n][128..256) = u·msgW1r ; CT[n][128..256) = u·msgW1c + mB1
    for (int g = 0; g < 2; ++g) {
        int ksOff = g*4;
        unsigned short* Out = (g ? CT : RT) + 128;
        #pragma unroll
        for (int i = 0; i < 8; ++i) acc[i] = (f32x4){0.f,0.f,0.f,0.f};
        for (int ks = 0; ks < 4; ++ks) {
            short8 a0 = *(const short8*)&HU.UF4[(ks*4+0)*64 + lane];
            short8 a1 = *(const short8*)&HU.UF4[(ks*4+1)*64 + lane];
            short8 a2 = *(const short8*)&HU.UF4[(ks*4+2)*64 + lane];
            short8 a3 = *(const short8*)&HU.UF4[(ks*4+3)*64 + lane];
            short8 b0 = *(const short8*)(mW1p + (size_t)(((wave*2+0)*8 + ksOff + ks)*64 + lane)*8);
            short8 b1v= *(const short8*)(mW1p + (size_t)(((wave*2+1)*8 + ksOff + ks)*64 + lane)*8);
            acc[0] = __builtin_amdgcn_mfma_f32_16x16x32_bf16(a0, b0, acc[0], 0,0,0);
            acc[1] = __builtin_amdgcn_mfma_f32_16x16x32_bf16(a0, b1v, acc[1], 0,0,0);
            acc[2] = __builtin_amdgcn_mfma_f32_16x16x32_bf16(a1, b0, acc[2], 0,0,0);
            acc[3] = __builtin_amdgcn_mfma_f32_16x16x32_bf16(a1, b1v, acc[3], 0,0,0);
            acc[4] = __builtin_amdgcn_mfma_f32_16x16x32_bf16(a2, b0, acc[4], 0,0,0);
            acc[5] = __builtin_amdgcn_mfma_f32_16x16x32_bf16(a2, b1v, acc[5], 0,0,0);
            acc[6] = __builtin_amdgcn_mfma_f32_16x16x32_bf16(a3, b0, acc[6], 0,0,0);
            acc[7] = __builtin_amdgcn_mfma_f32_16x16x32_bf16(a3, b1v, acc[7], 0,0,0);
        }
        #pragma unroll
        for (int b = 0; b < 2; ++b) {
            int n = (wave*2 + b)*16 + lr;
            float bb = g ? mB1[n] : 0.f;
            #pragma unroll
            for (int mt = 0; mt < 4; ++mt) {
                f32x4 v = acc[mt*2 + b];
                #pragma unroll
                for (int r = 0; r < 4; ++r) {
                    int rowp = n0 + mt*16 + lq*4 + r;
                    unsigned hv = f2bf(v[r] + bb);
                    unsigned ph = (unsigned)__shfl_xor((int)hv, 1, 64);
                    if (!(lr & 1))
                        *(unsigned*)&Out[(size_t)rowp*RCS + n] = hv | (ph << 16);
                }
            }
        }
    }
}

// ---------------------------------------------------------------- stage 2
__global__ __launch_bounds__(256) void k_edge_enc(
    const float* __restrict__ pos, const int* __restrict__ row, const int* __restrict__ col,
    const float* __restrict__ w1, const float* __restrict__ b1,
    const float* __restrict__ w2, const float* __restrict__ b2,
    const float* __restrict__ lg, const float* __restrict__ lb,
    float* __restrict__ ef)
{
    int e = blockIdx.x*256 + threadIdx.x;
    if (e >= NEDGE) return;
    int r = row[e], c = col[e];
    float e0 = pos[c*2]   - pos[r*2];
    float e1 = pos[c*2+1] - pos[r*2+1];
    float o0 = b2[0], o1 = b2[1];
    for (int j = 0; j < HD; ++j) {
        float h = fmaxf(e0*w1[j] + e1*w1[HD+j] + b1[j], 0.f);
        o0 += h*w2[j*2];
        o1 += h*w2[j*2+1];
    }
    float m  = 0.5f*(o0 + o1);
    float d0 = o0 - m, d1 = o1 - m;
    float v  = 0.5f*(d0*d0 + d1*d1);
    float sd = sqrtf(v + 1e-5f);
    ef[e*2]   = d0/sd*lg[0] + lb[0];
    ef[e*2+1] = d1/sd*lg[1] + lb[1];
}

// ---------------------------------------------------------------- merged counts
__global__ void k_count2(const int* __restrict__ col, const float* __restrict__ pos,
                         int* __restrict__ cnt, int* __restrict__ gcnt)
{
    int e = blockIdx.x*256 + threadIdx.x;
    if (e < NEDGE) atomicAdd(&cnt[col[e]], 1);
    if (e < NN) {
        int cx = min(max((int)(pos[e*2]  *(float)GDIM), 0), GDIM-1);
        int cy = min(max((int)(pos[e*2+1]*(float)GDIM), 0), GDIM-1);
        atomicAdd(&gcnt[cy*GDIM + cx], 1);
    }
}

// ---------------------------------------------------------------- merged scans
__global__ __launch_bounds__(256) void k_scan2(
    const int* __restrict__ cnt, int* __restrict__ head,
    const int* __restrict__ gcnt, int* __restrict__ gstart, int* __restrict__ ghead)
{
    __shared__ int ls[257];
    int tid = threadIdx.x;
    if (blockIdx.x == 0) {
        int base = tid * (NN/256);
        int s = 0;
        for (int i = 0; i < NN/256; ++i) s += cnt[base + i];
        ls[tid+1] = s;
        if (tid == 0) ls[0] = 0;
        __syncthreads();
        if (tid == 0) for (int i = 1; i <= 256; ++i) ls[i] += ls[i-1];
        __syncthreads();
        int run = ls[tid];
        for (int i = 0; i < NN/256; ++i) {
            head[base + i] = run;
            run += cnt[base + i];
        }
    } else {
        int base = tid * 4;
        int s = 0;
        for (int i = 0; i < 4; ++i) s += gcnt[base + i];
        ls[tid+1] = s;
        if (tid == 0) ls[0] = 0;
        __syncthreads();
        if (tid == 0) for (int i = 1; i <= 256; ++i) ls[i] += ls[i-1];
        __syncthreads();
        int run = ls[tid];
        for (int i = 0; i < 4; ++i) {
            gstart[base+i] = run; ghead[base+i] = run;
            run += gcnt[base+i];
        }
        if (tid == 255) gstart[GDIM*GDIM] = run;
    }
}

// ---------------------------------------------------------------- merged scatters
__global__ __launch_bounds__(256) void k_scatter2(
    const int* __restrict__ col, const float* __restrict__ pos,
    int* __restrict__ head, int* __restrict__ perm,
    int* __restrict__ ghead, float2* __restrict__ psort, int* __restrict__ pidx)
{
    int e = blockIdx.x*256 + threadIdx.x;
    if (e < NEDGE) {
        int p = atomicAdd(&head[col[e]], 1);
        perm[p] = e;
    }
    if (e < NN) {
        float px = pos[e*2], py = pos[e*2+1];
        int cx = min(max((int)(px*(float)GDIM), 0), GDIM-1);
        int cy = min(max((int)(py*(float)GDIM), 0), GDIM-1);
        int p = atomicAdd(&ghead[cy*GDIM + cx], 1);
        float2 pp; pp.x = px; pp.y = py;
        psort[p] = pp;
        pidx[p] = e;
    }
}

// ---------------------------------------------------------------- grid kNN select -> coef scatter
__global__ __launch_bounds__(256) void k_knnsel(
    const float* __restrict__ pos, const int* __restrict__ gstart,
    const float2* __restrict__ psort, const int* __restrict__ pidx,
    float* __restrict__ coef)
{
    int r = blockIdx.x*256 + threadIdx.x;
    int ni = (int)(2.0*r + (double)r/8191.0);
    float qx = pos[ni*2], qy = pos[ni*2+1];
    float s2 = qx*qx + qy*qy;
    int cx = min(max((int)(qx*(float)GDIM), 0), GDIM-1);
    int cy = min(max((int)(qy*(float)GDIM), 0), GDIM-1);
    const float h = 1.f/(float)GDIM;
    unsigned long long k0 = ~0ull, k1 = ~0ull, k2 = ~0ull;
    for (int rr = 0; rr < GDIM; ++rr) {
        if (rr > 0 && k2 != ~0ull) {
            float bound = rr*h;
            float d3 = __uint_as_float((unsigned)(k2 >> 32));
            if (d3 < bound*bound*0.9999f) break;
        }
        int ylo = max(cy-rr, 0), yhi = min(cy+rr, GDIM-1);
        int xlo = max(cx-rr, 0), xhi = min(cx+rr, GDIM-1);
        for (int gy = ylo; gy <= yhi; ++gy) {
            bool yedge = (gy == cy-rr) || (gy == cy+rr);
            for (int gx = xlo; gx <= xhi; ++gx) {
                if (!yedge && gx != cx-rr && gx != cx+rr) continue;
                int cell = gy*GDIM + gx;
                int s = gstart[cell], e = gstart[cell+1];
                for (; s < e; ++s) {
                    float2 p = psort[s];
                    float sc = p.x*p.x + p.y*p.y;
                    float dt = qx*p.x + qy*p.y;
                    float d2 = fmaxf(s2 + sc - 2.f*dt, 0.f);
                    unsigned long long key =
                        ((unsigned long long)__float_as_uint(d2) << 32) | (unsigned)pidx[s];
                    unsigned long long a0 = umin64(k0, key);
                    unsigned long long a1 = umin64(k1, umax64(k0, key));
                    unsigned long long a2 = umin64(k2, umax64(k1, key));
                    k0 = a0; k1 = a1; k2 = a2;
                }
            }
        }
    }
    float d0 = __uint_as_float((unsigned)(k0 >> 32));
    float d1 = __uint_as_float((unsigned)(k1 >> 32));
    float d2 = __uint_as_float((unsigned)(k2 >> 32));
    float w0 = 1.f/(sqrtf(d0) + 1e-8f);
    float w1 = 1.f/(sqrtf(d1) + 1e-8f);
    float w2 = 1.f/(sqrtf(d2) + 1e-8f);
    float ws = w0 + w1 + w2;
    atomicAdd(&coef[(int)(unsigned)(k0 & 0xffffffffu)], w0/ws);
    atomicAdd(&coef[(int)(unsigned)(k1 & 0xffffffffu)], w1/ws);
    atomicAdd(&coef[(int)(unsigned)(k2 & 0xffffffffu)], w2/ws);
}

// ---------------------------------------------------------------- layer-0 h aggregation
__global__ __launch_bounds__(256) void k_hagg0(
    const unsigned short* __restrict__ RT, const unsigned short* __restrict__ CT,
    const float* __restrict__ ef,
    const int* __restrict__ row, const int* __restrict__ col,
    const int* __restrict__ perm,
    const float* __restrict__ mW1e,
    float* __restrict__ agg)
{
    __shared__ float Ms[64][132];
    __shared__ float Pw[256];
    __shared__ float Es[64][2];
    __shared__ int colS[64], rowS[64], eS[64];
    int tid = threadIdx.x;
    int e0  = blockIdx.x * 64;
    if (tid < 64) {
        int e = perm[e0 + tid];
        eS[tid] = e; colS[tid] = col[e]; rowS[tid] = row[e];
    }
    for (int t = tid; t < 256; t += 256) Pw[t] = mW1e[t];
    __syncthreads();
    if (tid < 128) { Es[tid>>1][tid&1] = ef[(size_t)eS[tid>>1]*2 + (tid&1)]; }
    __syncthreads();

    int mP = (tid >> 6)*16 + (tid & 15);
    int ccB = ((tid & 63) >> 4)*8;
    float e0v = Es[mP][0], e1v = Es[mP][1];
    const unsigned short* rbase = RT + (size_t)rowS[mP]*RCS + 128;
    const unsigned short* cbase = CT + (size_t)colS[mP]*RCS + 128;
    #pragma unroll
    for (int s4 = 0; s4 < 4; ++s4) {
        int cc = s4*32 + ccB;
        uint4 ra = *(const uint4*)(rbase + cc);
        uint4 cb = *(const uint4*)(cbase + cc);
        float rf[8], cf[8];
        unp8(ra, rf); unp8(cb, cf);
        float4 o0, o1;
        o0.x = fmaxf(rf[0]+cf[0]+e0v*Pw[cc+0]+e1v*Pw[128+cc+0], 0.f);
        o0.y = fmaxf(rf[1]+cf[1]+e0v*Pw[cc+1]+e1v*Pw[128+cc+1], 0.f);
        o0.z = fmaxf(rf[2]+cf[2]+e0v*Pw[cc+2]+e1v*Pw[128+cc+2], 0.f);
        o0.w = fmaxf(rf[3]+cf[3]+e0v*Pw[cc+3]+e1v*Pw[128+cc+3], 0.f);
        o1.x = fmaxf(rf[4]+cf[4]+e0v*Pw[cc+4]+e1v*Pw[128+cc+4], 0.f);
        o1.y = fmaxf(rf[5]+cf[5]+e0v*Pw[cc+5]+e1v*Pw[128+cc+5], 0.f);
        o1.z = fmaxf(rf[6]+cf[6]+e0v*Pw[cc+6]+e1v*Pw[128+cc+6], 0.f);
        o1.w = fmaxf(rf[7]+cf[7]+e0v*Pw[cc+7]+e1v*Pw[128+cc+7], 0.f);
        *(float4*)&Ms[mP][cc]   = o0;
        *(float4*)&Ms[mP][cc+4] = o1;
    }
    __syncthreads();

    {
        int n = tid & 127, hh = tid >> 7;
        int m0 = hh*32;
        float accv = 0.f;
        int cur = colS[m0];
        for (int m = m0; m < m0 + 32; ++m) {
            int cm = colS[m];
            if (cm != cur) {
                atomicAdd(&agg[(size_t)cur*HD + n], accv);
                accv = 0.f; cur = cm;
            }
            accv += Ms[m][n];
        }
        atomicAdd(&agg[(size_t)cur*HD + n], accv);
    }
}

union MsHFu { uint4 HF4[1024]; float Ms[64][132]; };

// ---------------------------------------------------------------- FUSED edge(l) + msg(l+1), combined tables
__global__ __launch_bounds__(256) void k_edgemsg2(
    const unsigned short* __restrict__ RT, const unsigned short* __restrict__ CT,
    float* __restrict__ ef,
    const int* __restrict__ row, const int* __restrict__ col,
    const int* __restrict__ perm,
    const float* __restrict__ eW1e,
    const unsigned short* __restrict__ eW2p, const float* __restrict__ eB2,
    const float* __restrict__ elg, const float* __restrict__ elb,
    const float* __restrict__ mW1e,
    float* __restrict__ agg, int writeEf)
{
    __shared__ MsHFu MU;
    __shared__ float Pew[256], Pmw[256];
    __shared__ float Es[64][2];
    __shared__ int colS[64], rowS[64], eS[64];
    int tid = threadIdx.x;
    int e0  = blockIdx.x * 64;
    if (tid < 64) {
        int e = perm[e0 + tid];
        eS[tid] = e; colS[tid] = col[e]; rowS[tid] = row[e];
    }
    for (int t = tid; t < 256; t += 256) { Pew[t] = eW1e[t]; Pmw[t] = mW1e[t]; }
    __syncthreads();

    int mP = (tid >> 6)*16 + (tid & 15);
    int ccB = ((tid & 63) >> 4)*8;
    const unsigned short* rbase = RT + (size_t)rowS[mP]*RCS;
    const unsigned short* cbase = CT + (size_t)colS[mP]*RCS;
    // prefetch msg-phase gathers (high halves) — hide behind edge phase
    uint4 regR[4], regC[4];
    #pragma unroll
    for (int s4 = 0; s4 < 4; ++s4) {
        int cc = s4*32 + ccB;
        regR[s4] = *(const uint4*)(rbase + 128 + cc);
        regC[s4] = *(const uint4*)(cbase + 128 + cc);
    }
    if (tid < 128) { Es[tid>>1][tid&1] = ef[(size_t)eS[tid>>1]*2 + (tid&1)]; }
    __syncthreads();

    int lane = tid & 63, wave = tid >> 6;
    int lr = lane & 15, lq = lane >> 4;

    // ---- edge phase: build He (bf16, fragment-major) from low halves
    {
        float e0v = Es[mP][0], e1v = Es[mP][1];
        #pragma unroll
        for (int s4 = 0; s4 < 4; ++s4) {
            int s = tid + s4*256;
            int cc = s4*32 + ccB;
            uint4 ra = *(const uint4*)(rbase + cc);
            uint4 cb = *(const uint4*)(cbase + cc);
            float rf[8], cf[8];
            unp8(ra, rf); unp8(cb, cf);
            unsigned short hb[8];
            #pragma unroll
            for (int j = 0; j < 8; ++j) {
                int n = cc + j;
                float o = rf[j] + cf[j] + e0v*Pew[n] + e1v*Pew[128+n];
                hb[j] = f2bf(fmaxf(o, 0.f));
            }
            uint4 pk;
            pk.x = hb[0] | ((unsigned)hb[1]<<16); pk.y = hb[2] | ((unsigned)hb[3]<<16);
            pk.z = hb[4] | ((unsigned)hb[5]<<16); pk.w = hb[6] | ((unsigned)hb[7]<<16);
            MU.HF4[s] = pk;
        }
    }
    __syncthreads();

    // edge stage-2: per-wave 16 edges, 16-col zero-padded tile
    f32x4 a2 = (f32x4){0.f,0.f,0.f,0.f};
    for (int ks = 0; ks < 4; ++ks) {
        short8 a = *(const short8*)&MU.HF4[(ks*4 + wave)*64 + lane];
        short8 b = *(const short8*)(eW2p + (size_t)(ks*64 + lane)*8);
        a2 = __builtin_amdgcn_mfma_f32_16x16x32_bf16(a, b, a2, 0,0,0);
    }
    if (lr < 2) {
        int d = lr;
        float bb = eB2[d];
        float gg = elg[d], bl = elb[d];
        #pragma unroll
        for (int r = 0; r < 4; ++r) {
            int m = wave*16 + lq*4 + r;
            float rv = Es[m][d] + a2[r] + bb;
            float other = __shfl_xor(rv, 1, 64);
            float mm = 0.5f*(rv + other);
            float dr = rv - mm, dro = other - mm;
            float vv = 0.5f*(dr*dr + dro*dro);
            float outv = dr / sqrtf(vv + 1e-5f) * gg + bl;
            Es[m][d] = outv;
            if (writeEf) ef[(size_t)eS[m]*2 + d] = outv;
        }
    }
    __syncthreads();

    // ---- msg phase from prefetched high halves + NEW ef
    {
        float e0v = Es[mP][0], e1v = Es[mP][1];
        #pragma unroll
        for (int s4 = 0; s4 < 4; ++s4) {
            int cc = s4*32 + ccB;
            float rf[8], cf[8];
            unp8(regR[s4], rf); unp8(regC[s4], cf);
            float4 o0, o1;
            o0.x = fmaxf(rf[0]+cf[0]+e0v*Pmw[cc+0]+e1v*Pmw[128+cc+0], 0.f);
            o0.y = fmaxf(rf[1]+cf[1]+e0v*Pmw[cc+1]+e1v*Pmw[128+cc+1], 0.f);
            o0.z = fmaxf(rf[2]+cf[2]+e0v*Pmw[cc+2]+e1v*Pmw[128+cc+2], 0.f);
            o0.w = fmaxf(rf[3]+cf[3]+e0v*Pmw[cc+3]+e1v*Pmw[128+cc+3], 0.f);
            o1.x = fmaxf(rf[4]+cf[4]+e0v*Pmw[cc+4]+e1v*Pmw[128+cc+4], 0.f);
            o1.y = fmaxf(rf[5]+cf[5]+e0v*Pmw[cc+5]+e1v*Pmw[128+cc+5], 0.f);
            o1.z = fmaxf(rf[6]+cf[6]+e0v*Pmw[cc+6]+e1v*Pmw[128+cc+6], 0.f);
            o1.w = fmaxf(rf[7]+cf[7]+e0v*Pmw[cc+7]+e1v*Pmw[128+cc+7], 0.f);
            *(float4*)&MU.Ms[mP][cc]   = o0;
            *(float4*)&MU.Ms[mP][cc+4] = o1;
        }
    }
    __syncthreads();

    {
        int n = tid & 127, hh = tid >> 7;
        int m0 = hh*32;
        float accv = 0.f;
        int cur = colS[m0];
        for (int m = m0; m < m0 + 32; ++m) {
            int cm = colS[m];
            if (cm != cur) {
                atomicAdd(&agg[(size_t)cur*HD + n], accv);
                accv = 0.f; cur = cm;
            }
            accv += MU.Ms[m][n];
        }
        atomicAdd(&agg[(size_t)cur*HD + n], accv);
    }
}

// ---------------------------------------------------------------- node update
union XRu { unsigned short Xs[64][264]; float Rs[64][132]; };

__global__ __launch_bounds__(256) void k_node_mfma(
    float* __restrict__ u, unsigned short* __restrict__ u16,
    float* __restrict__ agg, const int* __restrict__ cnt,
    const unsigned short* __restrict__ W1p, const float* __restrict__ B1,
    const unsigned short* __restrict__ W2p, const float* __restrict__ B2,
    const float* __restrict__ lg, const float* __restrict__ lb,
    const unsigned short* __restrict__ mW2pC, const float* __restrict__ mB2C,
    int doExtra,
    const unsigned short* __restrict__ eW1p, const float* __restrict__ eB1c,
    const unsigned short* __restrict__ mW1pN, const float* __restrict__ mB1N,
    unsigned short* __restrict__ RT, unsigned short* __restrict__ CT)
{
    __shared__ XRu XR;
    __shared__ HUu HU;
    __shared__ float red[64][4];
    __shared__ float mstat[64], sstat[64];
    __shared__ float invS[64], fS[64];
    int tid = threadIdx.x;
    int n0  = blockIdx.x * 64;
    for (int t = tid; t < 1024; t += 256) {
        int el = t >> 4, kc = t & 15;
        uint4 v = *(const uint4*)(u16 + (size_t)(n0+el)*HD + kc*8);
        *(uint4*)&XR.Xs[el][kc*8] = v;
    }
    if (tid < 64) {
        int c = cnt[n0 + tid];
        invS[tid] = 1.f / fmaxf((float)c, 1.f);
        fS[tid] = (c > 0) ? 1.f : 0.f;
    }
    for (int t = tid; t < 1024; t += 256) {
        int lane_s = t & 63, ksmt = t >> 6;
        int ks = ksmt >> 2, mt = ksmt & 3;
        int el = mt*16 + (lane_s & 15);
        int cc = ks*32 + (lane_s >> 4)*8;
        const float* src = agg + (size_t)(n0+el)*HD + cc;
        float4 a = *(const float4*)src;
        float4 b = *(const float4*)(src + 4);
        uint4 pk;
        pk.x = f2bf(a.x) | ((unsigned)f2bf(a.y) << 16);
        pk.y = f2bf(a.z) | ((unsigned)f2bf(a.w) << 16);
        pk.z = f2bf(b.x) | ((unsigned)f2bf(b.y) << 16);
        pk.w = f2bf(b.z) | ((unsigned)f2bf(b.w) << 16);
        HU.UF4[t] = pk;
    }
    __syncthreads();

    int lane = tid & 63, wave = tid >> 6;
    int lr = lane & 15, lq = lane >> 4;
    f32x4 acc[8];

    #pragma unroll
    for (int i = 0; i < 8; ++i) acc[i] = (f32x4){0.f,0.f,0.f,0.f};
    for (int ks = 0; ks < 4; ++ks) {
        short8 a0 = *(const short8*)&HU.UF4[(ks*4+0)*64 + lane];
        short8 a1 = *(const short8*)&HU.UF4[(ks*4+1)*64 + lane];
        short8 a2 = *(const short8*)&HU.UF4[(ks*4+2)*64 + lane];
        short8 a3 = *(const short8*)&HU.UF4[(ks*4+3)*64 + lane];
        short8 b0 = *(const short8*)(mW2pC + (size_t)(((wave*2+0)*4 + ks)*64 + lane)*8);
        short8 b1 = *(const short8*)(mW2pC + (size_t)(((wave*2+1)*4 + ks)*64 + lane)*8);
        acc[0] = __builtin_amdgcn_mfma_f32_16x16x32_bf16(a0, b0, acc[0], 0,0,0);
        acc[1] = __builtin_amdgcn_mfma_f32_16x16x32_bf16(a0, b1, acc[1], 0,0,0);
        acc[2] = __builtin_amdgcn_mfma_f32_16x16x32_bf16(a1, b0, acc[2], 0,0,0);
        acc[3] = __builtin_amdgcn_mfma_f32_16x16x32_bf16(a1, b1, acc[3], 0,0,0);
        acc[4] = __builtin_amdgcn_mfma_f32_16x16x32_bf16(a2, b0, acc[4], 0,0,0);
        acc[5] = __builtin_amdgcn_mfma_f32_16x16x32_bf16(a2, b1, acc[5], 0,0,0);
        acc[6] = __builtin_amdgcn_mfma_f32_16x16x32_bf16(a3, b0, acc[6], 0,0,0);
        acc[7] = __builtin_amdgcn_mfma_f32_16x16x32_bf16(a3, b1, acc[7], 0,0,0);
    }
    #pragma unroll
    for (int b = 0; b < 2; ++b) {
        int n = (wave*2 + b)*16 + lr;
        float bb = mB2C[n];
        #pragma unroll
        for (int mt = 0; mt < 4; ++mt) {
            f32x4 v = acc[mt*2 + b];
            #pragma unroll
            for (int r = 0; r < 4; ++r) {
                int m = mt*16 + lq*4 + r;
                float val = v[r]*invS[m] + fS[m]*bb;
                unsigned hv = f2bf(val);
                unsigned ph = (unsigned)__shfl_xor((int)hv, 1, 64);
                if (!(lr & 1))
                    *(unsigned*)&XR.Xs[m][128 + n] = hv | (ph << 16);
            }
        }
    }
    __syncthreads();

    #pragma unroll
    for (int i = 0; i < 8; ++i) acc[i] = (f32x4){0.f,0.f,0.f,0.f};
    for (int ks = 0; ks < 8; ++ks) {
        short8 a0 = *(const short8*)&XR.Xs[ 0 + lr][ks*32 + lq*8];
        short8 a1 = *(const short8*)&XR.Xs[16 + lr][ks*32 + lq*8];
        short8 a2 = *(const short8*)&XR.Xs[32 + lr][ks*32 + lq*8];
        short8 a3 = *(const short8*)&XR.Xs[48 + lr][ks*32 + lq*8];
        short8 b0 = *(const short8*)(W1p + (size_t)(((wave*2+0)*8 + ks)*64 + lane)*8);
        short8 b1 = *(const short8*)(W1p + (size_t)(((wave*2+1)*8 + ks)*64 + lane)*8);
        acc[0] = __builtin_amdgcn_mfma_f32_16x16x32_bf16(a0, b0, acc[0], 0,0,0);
        acc[1] = __builtin_amdgcn_mfma_f32_16x16x32_bf16(a0, b1, acc[1], 0,0,0);
        acc[2] = __builtin_amdgcn_mfma_f32_16x16x32_bf16(a1, b0, acc[2], 0,0,0);
        acc[3] = __builtin_amdgcn_mfma_f32_16x16x32_bf16(a1, b1, acc[3], 0,0,0);
        acc[4] = __builtin_amdgcn_mfma_f32_16x16x32_bf16(a2, b0, acc[4], 0,0,0);
        acc[5] = __builtin_amdgcn_mfma_f32_16x16x32_bf16(a2, b1, acc[5], 0,0,0);
        acc[6] = __builtin_amdgcn_mfma_f32_16x16x32_bf16(a3, b0, acc[6], 0,0,0);
        acc[7] = __builtin_amdgcn_mfma_f32_16x16x32_bf16(a3, b1, acc[7], 0,0,0);
    }
    #pragma unroll
    for (int b = 0; b < 2; ++b) {
        int n = (wave*2 + b)*16 + lr;
        float bb = B1[n];
        #pragma unroll
        for (int mt = 0; mt < 4; ++mt) {
            f32x4 v = acc[mt*2 + b];
            #pragma unroll
            for (int r = 0; r < 4; ++r) {
                int m = mt*16 + lq*4 + r;
                HU.Hs[m][n] = f2bf(fmaxf(v[r] + bb, 0.f));
            }
        }
    }
    __syncthreads();

    #pragma unroll
    for (int i = 0; i < 8; ++i) acc[i] = (f32x4){0.f,0.f,0.f,0.f};
    for (int ks = 0; ks < 4; ++ks) {
        short8 a0 = *(const short8*)&HU.Hs[ 0 + lr][ks*32 + lq*8];
        short8 a1 = *(const short8*)&HU.Hs[16 + lr][ks*32 + lq*8];
        short8 a2 = *(const short8*)&HU.Hs[32 + lr][ks*32 + lq*8];
        short8 a3 = *(const short8*)&HU.Hs[48 + lr][ks*32 + lq*8];
        short8 b0 = *(const short8*)(W2p + (size_t)(((wave*2+0)*4 + ks)*64 + lane)*8);
        short8 b1 = *(const short8*)(W2p + (size_t)(((wave*2+1)*4 + ks)*64 + lane)*8);
        acc[0] = __builtin_amdgcn_mfma_f32_16x16x32_bf16(a0, b0, acc[0], 0,0,0);
        acc[1] = __builtin_amdgcn_mfma_f32_16x16x32_bf16(a0, b1, acc[1], 0,0,0);
        acc[2] = __builtin_amdgcn_mfma_f32_16x16x32_bf16(a1, b0, acc[2], 0,0,0);
        acc[3] = __builtin_amdgcn_mfma_f32_16x16x32_bf16(a1, b1, acc[3], 0,0,0);
        acc[4] = __builtin_amdgcn_mfma_f32_16x16x32_bf16(a2, b0, acc[4], 0,0,0);
        acc[5] = __builtin_amdgcn_mfma_f32_16x16x32_bf16(a2, b1, acc[5], 0,0,0);
        acc[6] = __builtin_amdgcn_mfma_f32_16x16x32_bf16(a3, b0, acc[6], 0,0,0);
        acc[7] = __builtin_amdgcn_mfma_f32_16x16x32_bf16(a3, b1, acc[7], 0,0,0);
    }
    #pragma unroll
    for (int b = 0; b < 2; ++b) {
        int n = (wave*2 + b)*16 + lr;
        float bb = B2[n];
        #pragma unroll
        for (int mt = 0; mt < 4; ++mt) {
            f32x4 v = acc[mt*2 + b];
            #pragma unroll
            for (int r = 0; r < 4; ++r) {
                int m = mt*16 + lq*4 + r;
                XR.Rs[m][n] = u[(size_t)(n0+m)*HD + n] + v[r] + bb;
            }
        }
    }
    __syncthreads();
    {
        int m = tid >> 2, p = tid & 3;
        float s = 0.f;
        #pragma unroll 8
        for (int i = 0; i < 32; ++i) s += XR.Rs[m][p*32 + i];
        red[m][p] = s;
    }
    __syncthreads();
    if (tid < 64) mstat[tid] = (red[tid][0]+red[tid][1]+red[tid][2]+red[tid][3]) * (1.f/HD);
    __syncthreads();
    {
        int m = tid >> 2, p = tid & 3;
        float mm = mstat[m];
        float s = 0.f;
        #pragma unroll 8
        for (int i = 0; i < 32; ++i) { float d = XR.Rs[m][p*32 + i] - mm; s += d*d; }
        red[m][p] = s;
    }
    __syncthreads();
    if (tid < 64) sstat[tid] = sqrtf((red[tid][0]+red[tid][1]+red[tid][2]+red[tid][3]) * (1.f/HD) + 1e-5f);
    __syncthreads();
    for (int t = tid; t < 2048; t += 256) {
        int m = t >> 5, q = t & 31;
        int n = q*4;
        float mm = mstat[m], sd = sstat[m];
        float4 g4 = *(const float4*)(lg + n);
        float4 b4 = *(const float4*)(lb + n);
        float o0 = (XR.Rs[m][n+0]-mm)/sd*g4.x + b4.x;
        float o1 = (XR.Rs[m][n+1]-mm)/sd*g4.y + b4.y;
        float o2 = (XR.Rs[m][n+2]-mm)/sd*g4.z + b4.z;
        float o3 = (XR.Rs[m][n+3]-mm)/sd*g4.w + b4.w;
        float4 fo; fo.x=o0; fo.y=o1; fo.z=o2; fo.w=o3;
        *(float4*)(u + (size_t)(n0+m)*HD + n) = fo;
        uint2 pk; pk.x = f2bf(o0) | (f2bf(o1)<<16); pk.y = f2bf(o2) | (f2bf(o3)<<16);
        *(uint2*)(u16 + (size_t)(n0+m)*HD + n) = pk;
        if (doExtra) {
            int ksf = n >> 5, sub = (n >> 3) & 3;
            int slot = (ksf*4 + (m >> 4))*64 + ((m & 15) | (sub << 4));
            unsigned short* UF = (unsigned short*)HU.UF4;
            *(uint2*)&UF[slot*8 + (n & 7)] = pk;
        }
    }
    {
        float4 z; z.x=0.f; z.y=0.f; z.z=0.f; z.w=0.f;
        for (int t = tid; t < 2048; t += 256)
            *(float4*)(agg + (size_t)(n0 + (t>>5))*HD + (t&31)*4) = z;
    }
    if (!doExtra) return;
    __syncthreads();

    // 4 GEMMs into combined tables: RT low (RE), CT low (CE+eB1), RT high (RM), CT high (CM+mB1)
    for (int g = 0; g < 4; ++g) {
        const unsigned short* Bp = (g < 2) ? eW1p : mW1pN;
        int ksOff = (g & 1) * 4;
        unsigned short* Out = ((g & 1) ? CT : RT) + ((g < 2) ? 0 : 128);
        const float* bias = (g == 1) ? eB1c : (g == 3) ? mB1N : (const float*)nullptr;
        #pragma unroll
        for (int i = 0; i < 8; ++i) acc[i] = (f32x4){0.f,0.f,0.f,0.f};
        for (int ks = 0; ks < 4; ++ks) {
            short8 a0 = *(const short8*)&HU.UF4[(ks*4+0)*64 + lane];
            short8 a1 = *(const short8*)&HU.UF4[(ks*4+1)*64 + lane];
            short8 a2 = *(const short8*)&HU.UF4[(ks*4+2)*64 + lane];
            short8 a3 = *(const short8*)&HU.UF4[(ks*4+3)*64 + lane];
            short8 b0 = *(const short8*)(Bp + (size_t)(((wave*2+0)*8 + ksOff + ks)*64 + lane)*8);
            short8 b1 = *(const short8*)(Bp + (size_t)(((wave*2+1)*8 + ksOff + ks)*64 + lane)*8);
            acc[0] = __builtin_amdgcn_mfma_f32_16x16x32_bf16(a0, b0, acc[0], 0,0,0);
            acc[1] = __builtin_amdgcn_mfma_f32_16x16x32_bf16(a0, b1, acc[1], 0,0,0);
            acc[2] = __builtin_amdgcn_mfma_f32_16x16x32_bf16(a1, b0, acc[2], 0,0,0);
            acc[3] = __builtin_amdgcn_mfma_f32_16x16x32_bf16(a1, b1, acc[3], 0,0,0);
            acc[4] = __builtin_amdgcn_mfma_f32_16x16x32_bf16(a2, b0, acc[4], 0,0,0);
            acc[5] = __builtin_amdgcn_mfma_f32_16x16x32_bf16(a2, b1, acc[5], 0,0,0);
            acc[6] = __builtin_amdgcn_mfma_f32_16x16x32_bf16(a3, b0, acc[6], 0,0,0);
            acc[7] = __builtin_amdgcn_mfma_f32_16x16x32_bf16(a3, b1, acc[7], 0,0,0);
        }
        #pragma unroll
        for (int b = 0; b < 2; ++b) {
            int n = (wave*2 + b)*16 + lr;
            float bb = bias ? bias[n] : 0.f;
            #pragma unroll
            for (int mt = 0; mt < 4; ++mt) {
                f32x4 v = acc[mt*2 + b];
                #pragma unroll
                for (int r = 0; r < 4; ++r) {
                    int rowp = n0 + mt*16 + lq*4 + r;
                    unsigned hv = f2bf(v[r] + bb);
                    unsigned ph = (unsigned)__shfl_xor((int)hv, 1, 64);
                    if (!(lr & 1))
                        *(unsigned*)&Out[(size_t)rowp*RCS + n] = hv | (ph << 16);
                }
            }
        }
    }
}

// ---------------------------------------------------------------- stage 4+5: u3 = LN(MLP(u)), fused coef-weighted pool -> partial
__global__ __launch_bounds__(256) void k_m2_mfma(
    const unsigned short* __restrict__ u16,
    const unsigned short* __restrict__ W1p, const float* __restrict__ B1,
    const unsigned short* __restrict__ W2p, const float* __restrict__ B2,
    const float* __restrict__ lg, const float* __restrict__ lb,
    const float* __restrict__ coef, float* __restrict__ partial)
{
    __shared__ unsigned short Xs[64][136];
    __shared__ unsigned short Hs[64][136];
    __shared__ float Rs[64][132];
    __shared__ float red[64][4];
    __shared__ float mstat[64], sstat[64];
    __shared__ float zp[HD];
    int tid = threadIdx.x;
    int n0  = blockIdx.x * 64;
    if (tid < HD) zp[tid] = 0.f;
    for (int t = tid; t < 1024; t += 256) {
        int el = t >> 4, kc = t & 15;
        uint4 v = *(const uint4*)(u16 + (size_t)(n0+el)*HD + kc*8);
        *(uint4*)&Xs[el][kc*8] = v;
    }
    __syncthreads();

    int lane = tid & 63, wave = tid >> 6;
    int lr = lane & 15, lq = lane >> 4;
    f32x4 acc[8];
    #pragma unroll
    for (int i = 0; i < 8; ++i) acc[i] = (f32x4){0.f,0.f,0.f,0.f};
    for (int ks = 0; ks < 4; ++ks) {
        short8 a0 = *(const short8*)&Xs[ 0 + lr][ks*32 + lq*8];
        short8 a1 = *(const short8*)&Xs[16 + lr][ks*32 + lq*8];
        short8 a2 = *(const short8*)&Xs[32 + lr][ks*32 + lq*8];
        short8 a3 = *(const short8*)&Xs[48 + lr][ks*32 + lq*8];
        short8 b0 = *(const short8*)(W1p + (size_t)(((wave*2+0)*4 + ks)*64 + lane)*8);
        short8 b1 = *(const short8*)(W1p + (size_t)(((wave*2+1)*4 + ks)*64 + lane)*8);
        acc[0] = __builtin_amdgcn_mfma_f32_16x16x32_bf16(a0, b0, acc[0], 0,0,0);
        acc[1] = __builtin_amdgcn_mfma_f32_16x16x32_bf16(a0, b1, acc[1], 0,0,0);
        acc[2] = __builtin_amdgcn_mfma_f32_16x16x32_bf16(a1, b0, acc[2], 0,0,0);
        acc[3] = __builtin_amdgcn_mfma_f32_16x16x32_bf16(a1, b1, acc[3], 0,0,0);
        acc[4] = __builtin_amdgcn_mfma_f32_16x16x32_bf16(a2, b0, acc[4], 0,0,0);
        acc[5] = __builtin_amdgcn_mfma_f32_16x16x32_bf16(a2, b1, acc[5], 0,0,0);
        acc[6] = __builtin_amdgcn_mfma_f32_16x16x32_bf16(a3, b0, acc[6], 0,0,0);
        acc[7] = __builtin_amdgcn_mfma_f32_16x16x32_bf16(a3, b1, acc[7], 0,0,0);
    }
    #pragma unroll
    for (int b = 0; b < 2; ++b) {
        int n = (wave*2 + b)*16 + lr;
        float bb = B1[n];
        #pragma unroll
        for (int mt = 0; mt < 4; ++mt) {
            f32x4 v = acc[mt*2 + b];
            #pragma unroll
            for (int r = 0; r < 4; ++r) {
                int m = mt*16 + lq*4 + r;
                Hs[m][n] = f2bf(fmaxf(v[r] + bb, 0.f));
            }
        }
    }
    __syncthreads();

    #pragma unroll
    for (int i = 0; i < 8; ++i) acc[i] = (f32x4){0.f,0.f,0.f,0.f};
    for (int ks = 0; ks < 4; ++ks) {
        short8 a0 = *(const short8*)&Hs[ 0 + lr][ks*32 + lq*8];
        short8 a1 = *(const short8*)&Hs[16 + lr][ks*32 + lq*8];
        short8 a2 = *(const short8*)&Hs[32 + lr][ks*32 + lq*8];
        short8 a3 = *(const short8*)&Hs[48 + lr][ks*32 + lq*8];
        short8 b0 = *(const short8*)(W2p + (size_t)(((wave*2+0)*4 + ks)*64 + lane)*8);
        short8 b1 = *(const short8*)(W2p + (size_t)(((wave*2+1)*4 + ks)*64 + lane)*8);
        acc[0] = __builtin_amdgcn_mfma_f32_16x16x32_bf16(a0, b0, acc[0], 0,0,0);
        acc[1] = __builtin_amdgcn_mfma_f32_16x16x32_bf16(a0, b1, acc[1], 0,0,0);
        acc[2] = __builtin_amdgcn_mfma_f32_16x16x32_bf16(a1, b0, acc[2], 0,0,0);
        acc[3] = __builtin_amdgcn_mfma_f32_16x16x32_bf16(a1, b1, acc[3], 0,0,0);
        acc[4] = __builtin_amdgcn_mfma_f32_16x16x32_bf16(a2, b0, acc[4], 0,0,0);
        acc[5] = __builtin_amdgcn_mfma_f32_16x16x32_bf16(a2, b1, acc[5], 0,0,0);
        acc[6] = __builtin_amdgcn_mfma_f32_16x16x32_bf16(a3, b0, acc[6], 0,0,0);
        acc[7] = __builtin_amdgcn_mfma_f32_16x16x32_bf16(a3, b1, acc[7], 0,0,0);
    }
    #pragma unroll
    for (int b = 0; b < 2; ++b) {
        int n = (wave*2 + b)*16 + lr;
        float bb = B2[n];
        #pragma unroll
        for (int mt = 0; mt < 4; ++mt) {
            f32x4 v = acc[mt*2 + b];
            #pragma unroll
            for (int r = 0; r < 4; ++r) {
                int m = mt*16 + lq*4 + r;
                Rs[m][n] = v[r] + bb;
            }
        }
    }
    __syncthreads();
    {
        int m = tid >> 2, p = tid & 3;
        float s = 0.f;
        #pragma unroll 8
        for (int i = 0; i < 32; ++i) s += Rs[m][p*32 + i];
        red[m][p] = s;
    }
    __syncthreads();
    if (tid < 64) mstat[tid] = (red[tid][0]+red[tid][1]+red[tid][2]+red[tid][3]) * (1.f/HD);
    __syncthreads();
    {
        int m = tid >> 2, p = tid & 3;
        float mm = mstat[m];
        float s = 0.f;
        #pragma unroll 8
        for (int i = 0; i < 32; ++i) { float d = Rs[m][p*32 + i] - mm; s += d*d; }
        red[m][p] = s;
    }
    __syncthreads();
    if (tid < 64) sstat[tid] = sqrtf((red[tid][0]+red[tid][1]+red[tid][2]+red[tid][3]) * (1.f/HD) + 1e-5f);
    __syncthreads();
    {
        float4 a4; a4.x=0.f; a4.y=0.f; a4.z=0.f; a4.w=0.f;
        int q = tid & 31;
        int n = q*4;
        float4 g4 = *(const float4*)(lg + n);
        float4 b4 = *(const float4*)(lb + n);
        for (int t = tid; t < 2048; t += 256) {
            int m = t >> 5;
            float mm = mstat[m], sd = sstat[m];
            float cw = coef[n0 + m];
            float o0 = (Rs[m][n+0]-mm)/sd*g4.x + b4.x;
            float o1 = (Rs[m][n+1]-mm)/sd*g4.y + b4.y;
            float o2 = (Rs[m][n+2]-mm)/sd*g4.z + b4.z;
            float o3 = (Rs[m][n+3]-mm)/sd*g4.w + b4.w;
            a4.x += cw*o0; a4.y += cw*o1; a4.z += cw*o2; a4.w += cw*o3;
        }
        atomicAdd(&zp[n+0], a4.x);
        atomicAdd(&zp[n+1], a4.y);
        atomicAdd(&zp[n+2], a4.z);
        atomicAdd(&zp[n+3], a4.w);
    }
    __syncthreads();
    if (tid < HD) partial[(size_t)blockIdx.x*HD + tid] = zp[tid];
}

// ---------------------------------------------------------------- stage 6: reduce partials + output MLP
__global__ __launch_bounds__(128) void k_out(
    const float* __restrict__ partial,
    const float* __restrict__ w1, const float* __restrict__ b1,
    const float* __restrict__ w2, const float* __restrict__ b2,
    float* __restrict__ out)
{
    __shared__ float zs[HD];
    __shared__ float hs[HD];
    int j = threadIdx.x;
    float s = 0.f;
    for (int p = 0; p < NN/64; ++p) s += partial[(size_t)p*HD + j];
    zs[j] = s * (1.f/NRED);
    __syncthreads();
    float o = b1[j];
    #pragma unroll 8
    for (int k = 0; k < HD; ++k) o += zs[k]*w1[k*HD + j];
    hs[j] = fmaxf(o, 0.f);
    __syncthreads();
    if (j < LATD) {
        float o2 = b2[j];
        #pragma unroll 8
        for (int k = 0; k < HD; ++k) o2 += hs[k]*w2[k*LATD + j];
        out[j] = o2;
    }
}

extern "C" void kernel_launch(void* const* d_in, const int* in_sizes, int n_in,
                              void* d_out, int out_size, void* d_ws, size_t ws_size,
                              hipStream_t stream)
{
    const float* x    = (const float*)d_in[0];
    const float* pos  = (const float*)d_in[1];
    const int*   eidx = (const int*)d_in[2];
    const int* row = eidx;
    const int* col = eidx + NEDGE;
    const float* m0_w1 = (const float*)d_in[3];
    const float* m0_b1 = (const float*)d_in[4];
    const float* m0_w2 = (const float*)d_in[5];
    const float* m0_b2 = (const float*)d_in[6];
    const float* ln0_g = (const float*)d_in[7];
    const float* ln0_b = (const float*)d_in[8];
    const float* m1_w1 = (const float*)d_in[9];
    const float* m1_b1 = (const float*)d_in[10];
    const float* m1_w2 = (const float*)d_in[11];
    const float* m1_b2 = (const float*)d_in[12];
    const float* ln1_g = (const float*)d_in[13];
    const float* ln1_b = (const float*)d_in[14];
    const float* g_msg_w1  = (const float*)d_in[15];
    const float* g_msg_b1  = (const float*)d_in[16];
    const float* g_msg_w2  = (const float*)d_in[17];
    const float* g_msg_b2  = (const float*)d_in[18];
    const float* g_node_w1 = (const float*)d_in[19];
    const float* g_node_b1 = (const float*)d_in[20];
    const float* g_node_w2 = (const float*)d_in[21];
    const float* g_node_b2 = (const float*)d_in[22];
    const float* g_edge_w1 = (const float*)d_in[23];
    const float* g_edge_b1 = (const float*)d_in[24];
    const float* g_edge_w2 = (const float*)d_in[25];
    const float* g_edge_b2 = (const float*)d_in[26];
    const float* g_lnn_g   = (const float*)d_in[27];
    const float* g_lnn_b   = (const float*)d_in[28];
    const float* g_lne_g   = (const float*)d_in[29];
    const float* g_lne_b   = (const float*)d_in[30];
    const float* m2_w1 = (const float*)d_in[31];
    const float* m2_b1 = (const float*)d_in[32];
    const float* m2_w2 = (const float*)d_in[33];
    const float* m2_b2 = (const float*)d_in[34];
    const float* ln2_g = (const float*)d_in[35];
    const float* ln2_b = (const float*)d_in[36];
    const float* op_w1 = (const float*)d_in[37];
    const float* op_b1 = (const float*)d_in[38];
    const float* op_w2 = (const float*)d_in[39];
    const float* op_b2 = (const float*)d_in[40];

    float* u    = (float*)d_ws;                       // NN*HD f32
    float* ef   = u + (size_t)NN*HD;                  // NEDGE*2
    float* agg  = ef + (size_t)NEDGE*2;               // NN*HD (h-sums)
    int*   cnt  = (int*)(agg + (size_t)NN*HD);        // NN
    int*   gcnt = cnt + NN;                           // 1024
    float* coef = (float*)(gcnt + 1024);              // NN
    int*   head = (int*)(coef + NN);                  // NN
    int*   perm = head + NN;                          // NEDGE
    float* partial = (float*)(perm + NEDGE);          // (NN/64)*HD
    int*   gstart = (int*)(partial + (NN/64)*HD);     // 1026
    int*   ghead  = gstart + 1026;                    // 1024
    int*   pidx   = ghead + 1024;                     // NN
    float2* psort = (float2*)(pidx + NN);             // NN float2
    unsigned short* u16 = (unsigned short*)(psort + NN);  // NN*HD bf16
    unsigned short* packs = u16 + (size_t)NN*HD;      // PK_TOTAL shorts
    unsigned short* msgW1p  = packs;
    unsigned short* msgW2p  = packs + 98304;
    unsigned short* edgeW1p = packs + 147456;
    unsigned short* nodeW1p = packs + 245760;
    unsigned short* nodeW2p = packs + 344064;
    unsigned short* edgeW2p = packs + 393216;
    unsigned short* m0w2p   = packs + 399360;
    unsigned short* m2w1p   = packs + 415744;
    unsigned short* m2w2p   = packs + 432128;
    unsigned short* RT = packs + PK_TOTAL;            // NN*RCS (combined RE|RM)
    unsigned short* CT = RT + (size_t)NN*RCS;         // NN*RCS (combined CE|CM)

    k_pack_all<<<(PK_TOTAL + 255)/256, 256, 0, stream>>>(
        g_msg_w1, g_msg_w2, g_edge_w1, g_node_w1, g_node_w2, g_edge_w2,
        m0_w2, m2_w1, m2_w2, packs);

    hipMemsetAsync(cnt, 0, (NN + 1024 + NN)*sizeof(int), stream);

    k_nenc_mfma<<<NN/64, 256, 0, stream>>>(x, m0_w1, m0_b1, m0w2p, m0_b2, ln0_g, ln0_b,
                                           msgW1p, g_msg_b1, u, u16, RT, CT, agg);
    k_edge_enc<<<NEDGE/256, 256, 0, stream>>>(pos, row, col, m1_w1, m1_b1, m1_w2, m1_b2,
                                              ln1_g, ln1_b, ef);

    k_count2<<<NEDGE/256, 256, 0, stream>>>(col, pos, cnt, gcnt);
    k_scan2<<<2, 256, 0, stream>>>(cnt, head, gcnt, gstart, ghead);
    k_scatter2<<<NEDGE/256, 256, 0, stream>>>(col, pos, head, perm, ghead, psort, pidx);
    k_knnsel<<<NRED/256, 256, 0, stream>>>(pos, gstart, psort, pidx, coef);

    // layer 0: h-aggregation (msg tables in RT/CT high halves)
    k_hagg0<<<NEDGE/64, 256, 0, stream>>>(RT, CT, ef, row, col, perm,
        g_msg_w1 + 256*HD, agg);
    k_node_mfma<<<NN/64, 256, 0, stream>>>(u, u16, agg, cnt,
        nodeW1p, g_node_b1, nodeW2p, g_node_b2, g_lnn_g, g_lnn_b,
        msgW2p, g_msg_b2,
        1, edgeW1p + 0*32768, g_edge_b1 + 0*HD, msgW1p + 1*32768, g_msg_b1 + 1*HD,
        RT, CT);

    // fused edge(l) + msg(l+1); edge(2) is dead code
    for (int l = 0; l < NLAYER-1; ++l) {
        k_edgemsg2<<<NEDGE/64, 256, 0, stream>>>(RT, CT, ef, row, col, perm,
            g_edge_w1 + (size_t)l*258*HD + 256*HD,
            edgeW2p + l*2048, g_edge_b2 + l*2, g_lne_g + l*2, g_lne_b + l*2,
            g_msg_w1 + (size_t)(l+1)*258*HD + 256*HD,
            agg, (l == 0) ? 1 : 0);
        int doExtra = (l == 0) ? 1 : 0;
        k_node_mfma<<<NN/64, 256, 0, stream>>>(u, u16, agg, cnt,
            nodeW1p + (l+1)*32768, g_node_b1 + (l+1)*HD,
            nodeW2p + (l+1)*16384, g_node_b2 + (l+1)*HD,
            g_lnn_g + (l+1)*HD, g_lnn_b + (l+1)*HD,
            msgW2p + (l+1)*16384, g_msg_b2 + (l+1)*HD,
            doExtra, edgeW1p + 1*32768, g_edge_b1 + 1*HD, msgW1p + 2*32768, g_msg_b1 + 2*HD,
            RT, CT);
    }

    k_m2_mfma<<<NN/64, 256, 0, stream>>>(u16, m2w1p, m2_b1, m2w2p, m2_b2, ln2_g, ln2_b,
                                         coef, partial);
    k_out<<<1, 128, 0, stream>>>(partial, op_w1, op_b1, op_w2, op_b2, (float*)d_out);
}

// Round 13
// 448.954 us; speedup vs baseline: 1.0316x; 1.0309x over previous
//
#include <hip/hip_runtime.h>
#include <cfloat>

#define NN     16384
#define NEDGE  262144
#define HD     128
#define NLAYER 3
#define NRED   8192
#define LATD   64
#define GDIM   32

typedef __attribute__((ext_vector_type(8))) short short8;
typedef __attribute__((ext_vector_type(4))) float f32x4;

__device__ __forceinline__ unsigned short f2bf(float f) {
    union { float f; unsigned u; } v; v.f = f;
    unsigned u = v.u;
    unsigned r = u + 0x7fff + ((u >> 16) & 1);
    return (unsigned short)(r >> 16);
}
__device__ __forceinline__ void unp8(uint4 v, float* f) {
    unsigned w0=v.x, w1=v.y, w2=v.z, w3=v.w;
    f[0]=__uint_as_float(w0<<16); f[1]=__uint_as_float(w0&0xffff0000u);
    f[2]=__uint_as_float(w1<<16); f[3]=__uint_as_float(w1&0xffff0000u);
    f[4]=__uint_as_float(w2<<16); f[5]=__uint_as_float(w2&0xffff0000u);
    f[6]=__uint_as_float(w3<<16); f[7]=__uint_as_float(w3&0xffff0000u);
}
__device__ __forceinline__ unsigned long long umin64(unsigned long long a, unsigned long long b) {
    return a < b ? a : b;
}
__device__ __forceinline__ unsigned long long umax64(unsigned long long a, unsigned long long b) {
    return a < b ? b : a;
}

// ---------------------------------------------------------------- consolidated weight packing
__device__ __forceinline__ unsigned short pack_std(const float* W, int ksteps, int q) {
    int j    = q & 7;
    int lane = (q >> 3) & 63;
    int ks   = (q >> 9) % ksteps;
    int nt   = q / (ksteps * 512);
    int k = ks*32 + (lane >> 4)*8 + j;
    int n = nt*16 + (lane & 15);
    return f2bf(W[k*128 + n]);
}
__device__ __forceinline__ unsigned short pack_w2e(const float* W, int q) {
    int j    = q & 7;
    int lane = (q >> 3) & 63;
    int ks   = q >> 9;
    int k = ks*32 + (lane >> 4)*8 + j;
    int n = lane & 15;
    return (n < 2) ? f2bf(W[k*2 + n]) : (unsigned short)0;
}

#define PK_TOTAL 448512
__global__ __launch_bounds__(256) void k_pack_all(
    const float* __restrict__ msgw1, const float* __restrict__ msgw2,
    const float* __restrict__ edgew1, const float* __restrict__ nodew1,
    const float* __restrict__ nodew2, const float* __restrict__ edgew2,
    const float* __restrict__ m0w2, const float* __restrict__ m2w1,
    const float* __restrict__ m2w2, unsigned short* __restrict__ P)
{
    int p = blockIdx.x*256 + threadIdx.x;
    if (p >= PK_TOTAL) return;
    unsigned short v;
    if (p < 98304) {
        int l = p / 32768, q = p % 32768;
        v = pack_std(msgw1 + (size_t)l*258*128, 8, q);
    } else if (p < 147456) {
        int t = p - 98304; int l = t / 16384, q = t % 16384;
        v = pack_std(msgw2 + (size_t)l*16384, 4, q);
    } else if (p < 245760) {
        int t = p - 147456; int l = t / 32768, q = t % 32768;
        v = pack_std(edgew1 + (size_t)l*258*128, 8, q);
    } else if (p < 344064) {
        int t = p - 245760; int l = t / 32768, q = t % 32768;
        v = pack_std(nodew1 + (size_t)l*256*128, 8, q);
    } else if (p < 393216) {
        int t = p - 344064; int l = t / 16384, q = t % 16384;
        v = pack_std(nodew2 + (size_t)l*16384, 4, q);
    } else if (p < 399360) {
        int t = p - 393216; int l = t / 2048, q = t % 2048;
        v = pack_w2e(edgew2 + (size_t)l*256, q);
    } else if (p < 415744) {
        v = pack_std(m0w2, 4, p - 399360);
    } else if (p < 432128) {
        v = pack_std(m2w1, 4, p - 415744);
    } else {
        v = pack_std(m2w2, 4, p - 432128);
    }
    P[p] = v;
}

union HUu { unsigned short Hs[64][136]; uint4 UF4[1024]; };

// ---------------------------------------------------------------- stage 1: node encoder (MFMA) + RM/CM precompute + agg zero
__global__ __launch_bounds__(256) void k_nenc_mfma(
    const float* __restrict__ x,
    const float* __restrict__ w1, const float* __restrict__ b1,
    const unsigned short* __restrict__ W2p, const float* __restrict__ B2,
    const float* __restrict__ lg, const float* __restrict__ lb,
    const unsigned short* __restrict__ mW1p, const float* __restrict__ mB1,
    float* __restrict__ u, unsigned short* __restrict__ u16,
    unsigned short* __restrict__ RM, unsigned short* __restrict__ CM,
    float* __restrict__ agg)
{
    __shared__ float xs[64][4];
    __shared__ float w1s[3][128];
    __shared__ float b1s[128];
    __shared__ HUu HU;
    __shared__ float Rs[64][132];
    __shared__ float red[64][4];
    __shared__ float mstat[64], sstat[64];
    int tid = threadIdx.x;
    int n0  = blockIdx.x * 64;
    {
        float4 z; z.x=0.f; z.y=0.f; z.z=0.f; z.w=0.f;
        for (int t = tid; t < 2048; t += 256)
            *(float4*)(agg + (size_t)(n0 + (t>>5))*HD + (t&31)*4) = z;
    }
    for (int t = tid; t < 384; t += 256) w1s[t >> 7][t & 127] = w1[t];
    if (tid < 128) b1s[tid] = b1[tid];
    for (int t = tid; t < 192; t += 256) xs[t/3][t%3] = x[(size_t)n0*3 + t];
    __syncthreads();
    {
        int m = tid >> 2, p0 = (tid & 3) * 32;
        float x0 = xs[m][0], x1 = xs[m][1], x2 = xs[m][2];
        for (int j = p0; j < p0 + 32; j += 2) {
            float h0 = fmaxf(b1s[j]   + x0*w1s[0][j]   + x1*w1s[1][j]   + x2*w1s[2][j],   0.f);
            float h1 = fmaxf(b1s[j+1] + x0*w1s[0][j+1] + x1*w1s[1][j+1] + x2*w1s[2][j+1], 0.f);
            *(unsigned*)&HU.Hs[m][j] = f2bf(h0) | ((unsigned)f2bf(h1) << 16);
        }
    }
    __syncthreads();

    int lane = tid & 63, wave = tid >> 6;
    int lr = lane & 15, lq = lane >> 4;
    f32x4 acc[8];
    #pragma unroll
    for (int i = 0; i < 8; ++i) acc[i] = (f32x4){0.f,0.f,0.f,0.f};
    for (int ks = 0; ks < 4; ++ks) {
        short8 a0 = *(const short8*)&HU.Hs[ 0 + lr][ks*32 + lq*8];
        short8 a1 = *(const short8*)&HU.Hs[16 + lr][ks*32 + lq*8];
        short8 a2 = *(const short8*)&HU.Hs[32 + lr][ks*32 + lq*8];
        short8 a3 = *(const short8*)&HU.Hs[48 + lr][ks*32 + lq*8];
        short8 b0 = *(const short8*)(W2p + (size_t)(((wave*2+0)*4 + ks)*64 + lane)*8);
        short8 b1v= *(const short8*)(W2p + (size_t)(((wave*2+1)*4 + ks)*64 + lane)*8);
        acc[0] = __builtin_amdgcn_mfma_f32_16x16x32_bf16(a0, b0, acc[0], 0,0,0);
        acc[1] = __builtin_amdgcn_mfma_f32_16x16x32_bf16(a0, b1v, acc[1], 0,0,0);
        acc[2] = __builtin_amdgcn_mfma_f32_16x16x32_bf16(a1, b0, acc[2], 0,0,0);
        acc[3] = __builtin_amdgcn_mfma_f32_16x16x32_bf16(a1, b1v, acc[3], 0,0,0);
        acc[4] = __builtin_amdgcn_mfma_f32_16x16x32_bf16(a2, b0, acc[4], 0,0,0);
        acc[5] = __builtin_amdgcn_mfma_f32_16x16x32_bf16(a2, b1v, acc[5], 0,0,0);
        acc[6] = __builtin_amdgcn_mfma_f32_16x16x32_bf16(a3, b0, acc[6], 0,0,0);
        acc[7] = __builtin_amdgcn_mfma_f32_16x16x32_bf16(a3, b1v, acc[7], 0,0,0);
    }
    #pragma unroll
    for (int b = 0; b < 2; ++b) {
        int n = (wave*2 + b)*16 + lr;
        float bb = B2[n];
        #pragma unroll
        for (int mt = 0; mt < 4; ++mt) {
            f32x4 v = acc[mt*2 + b];
            #pragma unroll
            for (int r = 0; r < 4; ++r) {
                int m = mt*16 + lq*4 + r;
                Rs[m][n] = v[r] + bb;
            }
        }
    }
    __syncthreads();
    {
        int m = tid >> 2, p = tid & 3;
        float s = 0.f;
        #pragma unroll 8
        for (int i = 0; i < 32; ++i) s += Rs[m][p*32 + i];
        red[m][p] = s;
    }
    __syncthreads();
    if (tid < 64) mstat[tid] = (red[tid][0]+red[tid][1]+red[tid][2]+red[tid][3]) * (1.f/HD);
    __syncthreads();
    {
        int m = tid >> 2, p = tid & 3;
        float mm = mstat[m];
        float s = 0.f;
        #pragma unroll 8
        for (int i = 0; i < 32; ++i) { float d = Rs[m][p*32 + i] - mm; s += d*d; }
        red[m][p] = s;
    }
    __syncthreads();
    if (tid < 64) sstat[tid] = sqrtf((red[tid][0]+red[tid][1]+red[tid][2]+red[tid][3]) * (1.f/HD) + 1e-5f);
    __syncthreads();
    for (int t = tid; t < 2048; t += 256) {
        int m = t >> 5, q = t & 31;
        int n = q*4;
        float mm = mstat[m], sd = sstat[m];
        float4 g4 = *(const float4*)(lg + n);
        float4 b4 = *(const float4*)(lb + n);
        float o0 = (Rs[m][n+0]-mm)/sd*g4.x + b4.x;
        float o1 = (Rs[m][n+1]-mm)/sd*g4.y + b4.y;
        float o2 = (Rs[m][n+2]-mm)/sd*g4.z + b4.z;
        float o3 = (Rs[m][n+3]-mm)/sd*g4.w + b4.w;
        float4 fo; fo.x=o0; fo.y=o1; fo.z=o2; fo.w=o3;
        *(float4*)(u + (size_t)(n0+m)*HD + n) = fo;
        uint2 pk; pk.x = f2bf(o0) | (f2bf(o1)<<16); pk.y = f2bf(o2) | (f2bf(o3)<<16);
        *(uint2*)(u16 + (size_t)(n0+m)*HD + n) = pk;
        int ksf = n >> 5, sub = (n >> 3) & 3;
        int slot = (ksf*4 + (m >> 4))*64 + ((m & 15) | (sub << 4));
        unsigned short* UF = (unsigned short*)HU.UF4;
        *(uint2*)&UF[slot*8 + (n & 7)] = pk;
    }
    __syncthreads();

    for (int g = 0; g < 2; ++g) {
        int ksOff = g*4;
        unsigned short* Out = g ? CM : RM;
        #pragma unroll
        for (int i = 0; i < 8; ++i) acc[i] = (f32x4){0.f,0.f,0.f,0.f};
        for (int ks = 0; ks < 4; ++ks) {
            short8 a0 = *(const short8*)&HU.UF4[(ks*4+0)*64 + lane];
            short8 a1 = *(const short8*)&HU.UF4[(ks*4+1)*64 + lane];
            short8 a2 = *(const short8*)&HU.UF4[(ks*4+2)*64 + lane];
            short8 a3 = *(const short8*)&HU.UF4[(ks*4+3)*64 + lane];
            short8 b0 = *(const short8*)(mW1p + (size_t)(((wave*2+0)*8 + ksOff + ks)*64 + lane)*8);
            short8 b1v= *(const short8*)(mW1p + (size_t)(((wave*2+1)*8 + ksOff + ks)*64 + lane)*8);
            acc[0] = __builtin_amdgcn_mfma_f32_16x16x32_bf16(a0, b0, acc[0], 0,0,0);
            acc[1] = __builtin_amdgcn_mfma_f32_16x16x32_bf16(a0, b1v, acc[1], 0,0,0);
            acc[2] = __builtin_amdgcn_mfma_f32_16x16x32_bf16(a1, b0, acc[2], 0,0,0);
            acc[3] = __builtin_amdgcn_mfma_f32_16x16x32_bf16(a1, b1v, acc[3], 0,0,0);
            acc[4] = __builtin_amdgcn_mfma_f32_16x16x32_bf16(a2, b0, acc[4], 0,0,0);
            acc[5] = __builtin_amdgcn_mfma_f32_16x16x32_bf16(a2, b1v, acc[5], 0,0,0);
            acc[6] = __builtin_amdgcn_mfma_f32_16x16x32_bf16(a3, b0, acc[6], 0,0,0);
            acc[7] = __builtin_amdgcn_mfma_f32_16x16x32_bf16(a3, b1v, acc[7], 0,0,0);
        }
        #pragma unroll
        for (int b = 0; b < 2; ++b) {
            int n = (wave*2 + b)*16 + lr;
            float bb = g ? mB1[n] : 0.f;
            #pragma unroll
            for (int mt = 0; mt < 4; ++mt) {
                f32x4 v = acc[mt*2 + b];
                #pragma unroll
                for (int r = 0; r < 4; ++r) {
                    int rowp = n0 + mt*16 + lq*4 + r;
                    unsigned hv = f2bf(v[r] + bb);
                    unsigned ph = (unsigned)__shfl_xor((int)hv, 1, 64);
                    if (!(lr & 1))
                        *(unsigned*)&Out[(size_t)rowp*HD + n] = hv | (ph << 16);
                }
            }
        }
    }
}

// ---------------------------------------------------------------- stage 2
__global__ __launch_bounds__(256) void k_edge_enc(
    const float* __restrict__ pos, const int* __restrict__ row, const int* __restrict__ col,
    const float* __restrict__ w1, const float* __restrict__ b1,
    const float* __restrict__ w2, const float* __restrict__ b2,
    const float* __restrict__ lg, const float* __restrict__ lb,
    float* __restrict__ ef)
{
    int e = blockIdx.x*256 + threadIdx.x;
    if (e >= NEDGE) return;
    int r = row[e], c = col[e];
    float e0 = pos[c*2]   - pos[r*2];
    float e1 = pos[c*2+1] - pos[r*2+1];
    float o0 = b2[0], o1 = b2[1];
    for (int j = 0; j < HD; ++j) {
        float h = fmaxf(e0*w1[j] + e1*w1[HD+j] + b1[j], 0.f);
        o0 += h*w2[j*2];
        o1 += h*w2[j*2+1];
    }
    float m  = 0.5f*(o0 + o1);
    float d0 = o0 - m, d1 = o1 - m;
    float v  = 0.5f*(d0*d0 + d1*d1);
    float sd = sqrtf(v + 1e-5f);
    ef[e*2]   = d0/sd*lg[0] + lb[0];
    ef[e*2+1] = d1/sd*lg[1] + lb[1];
}

// ---------------------------------------------------------------- merged counts (edge degree + grid cell)
__global__ void k_count2(const int* __restrict__ col, const float* __restrict__ pos,
                         int* __restrict__ cnt, int* __restrict__ gcnt)
{
    int e = blockIdx.x*256 + threadIdx.x;
    if (e < NEDGE) atomicAdd(&cnt[col[e]], 1);
    if (e < NN) {
        int cx = min(max((int)(pos[e*2]  *(float)GDIM), 0), GDIM-1);
        int cy = min(max((int)(pos[e*2+1]*(float)GDIM), 0), GDIM-1);
        atomicAdd(&gcnt[cy*GDIM + cx], 1);
    }
}

// ---------------------------------------------------------------- merged scans (block0: edge CSR; block1: grid)
__global__ __launch_bounds__(256) void k_scan2(
    const int* __restrict__ cnt, int* __restrict__ head,
    const int* __restrict__ gcnt, int* __restrict__ gstart, int* __restrict__ ghead)
{
    __shared__ int ls[257];
    int tid = threadIdx.x;
    if (blockIdx.x == 0) {
        int base = tid * (NN/256);
        int s = 0;
        for (int i = 0; i < NN/256; ++i) s += cnt[base + i];
        ls[tid+1] = s;
        if (tid == 0) ls[0] = 0;
        __syncthreads();
        if (tid == 0) for (int i = 1; i <= 256; ++i) ls[i] += ls[i-1];
        __syncthreads();
        int run = ls[tid];
        for (int i = 0; i < NN/256; ++i) {
            head[base + i] = run;
            run += cnt[base + i];
        }
    } else {
        int base = tid * 4;
        int s = 0;
        for (int i = 0; i < 4; ++i) s += gcnt[base + i];
        ls[tid+1] = s;
        if (tid == 0) ls[0] = 0;
        __syncthreads();
        if (tid == 0) for (int i = 1; i <= 256; ++i) ls[i] += ls[i-1];
        __syncthreads();
        int run = ls[tid];
        for (int i = 0; i < 4; ++i) {
            gstart[base+i] = run; ghead[base+i] = run;
            run += gcnt[base+i];
        }
        if (tid == 255) gstart[GDIM*GDIM] = run;
    }
}

// ---------------------------------------------------------------- merged scatters
__global__ __launch_bounds__(256) void k_scatter2(
    const int* __restrict__ col, const float* __restrict__ pos,
    int* __restrict__ head, int* __restrict__ perm,
    int* __restrict__ ghead, float2* __restrict__ psort, int* __restrict__ pidx)
{
    int e = blockIdx.x*256 + threadIdx.x;
    if (e < NEDGE) {
        int p = atomicAdd(&head[col[e]], 1);
        perm[p] = e;
    }
    if (e < NN) {
        float px = pos[e*2], py = pos[e*2+1];
        int cx = min(max((int)(px*(float)GDIM), 0), GDIM-1);
        int cy = min(max((int)(py*(float)GDIM), 0), GDIM-1);
        int p = atomicAdd(&ghead[cy*GDIM + cx], 1);
        float2 pp; pp.x = px; pp.y = py;
        psort[p] = pp;
        pidx[p] = e;
    }
}

// ---------------------------------------------------------------- grid kNN select -> coef scatter
__global__ __launch_bounds__(256) void k_knnsel(
    const float* __restrict__ pos, const int* __restrict__ gstart,
    const float2* __restrict__ psort, const int* __restrict__ pidx,
    float* __restrict__ coef)
{
    int r = blockIdx.x*256 + threadIdx.x;
    int ni = (int)(2.0*r + (double)r/8191.0);
    float qx = pos[ni*2], qy = pos[ni*2+1];
    float s2 = qx*qx + qy*qy;
    int cx = min(max((int)(qx*(float)GDIM), 0), GDIM-1);
    int cy = min(max((int)(qy*(float)GDIM), 0), GDIM-1);
    const float h = 1.f/(float)GDIM;
    unsigned long long k0 = ~0ull, k1 = ~0ull, k2 = ~0ull;
    for (int rr = 0; rr < GDIM; ++rr) {
        if (rr > 0 && k2 != ~0ull) {
            float bound = rr*h;
            float d3 = __uint_as_float((unsigned)(k2 >> 32));
            if (d3 < bound*bound*0.9999f) break;
        }
        int ylo = max(cy-rr, 0), yhi = min(cy+rr, GDIM-1);
        int xlo = max(cx-rr, 0), xhi = min(cx+rr, GDIM-1);
        for (int gy = ylo; gy <= yhi; ++gy) {
            bool yedge = (gy == cy-rr) || (gy == cy+rr);
            for (int gx = xlo; gx <= xhi; ++gx) {
                if (!yedge && gx != cx-rr && gx != cx+rr) continue;
                int cell = gy*GDIM + gx;
                int s = gstart[cell], e = gstart[cell+1];
                for (; s < e; ++s) {
                    float2 p = psort[s];
                    float sc = p.x*p.x + p.y*p.y;
                    float dt = qx*p.x + qy*p.y;
                    float d2 = fmaxf(s2 + sc - 2.f*dt, 0.f);
                    unsigned long long key =
                        ((unsigned long long)__float_as_uint(d2) << 32) | (unsigned)pidx[s];
                    unsigned long long a0 = umin64(k0, key);
                    unsigned long long a1 = umin64(k1, umax64(k0, key));
                    unsigned long long a2 = umin64(k2, umax64(k1, key));
                    k0 = a0; k1 = a1; k2 = a2;
                }
            }
        }
    }
    float d0 = __uint_as_float((unsigned)(k0 >> 32));
    float d1 = __uint_as_float((unsigned)(k1 >> 32));
    float d2 = __uint_as_float((unsigned)(k2 >> 32));
    float w0 = 1.f/(sqrtf(d0) + 1e-8f);
    float w1 = 1.f/(sqrtf(d1) + 1e-8f);
    float w2 = 1.f/(sqrtf(d2) + 1e-8f);
    float ws = w0 + w1 + w2;
    atomicAdd(&coef[(int)(unsigned)(k0 & 0xffffffffu)], w0/ws);
    atomicAdd(&coef[(int)(unsigned)(k1 & 0xffffffffu)], w1/ws);
    atomicAdd(&coef[(int)(unsigned)(k2 & 0xffffffffu)], w2/ws);
}

// ---------------------------------------------------------------- layer-0 h aggregation
__global__ __launch_bounds__(256) void k_hagg0(
    const unsigned short* __restrict__ RM, const unsigned short* __restrict__ CM,
    const float* __restrict__ ef,
    const int* __restrict__ row, const int* __restrict__ col,
    const int* __restrict__ perm,
    const float* __restrict__ mW1e,
    float* __restrict__ agg)
{
    __shared__ float Ms[64][132];
    __shared__ float Pw[256];
    __shared__ float Es[64][2];
    __shared__ int colS[64], rowS[64], eS[64];
    int tid = threadIdx.x;
    int e0  = blockIdx.x * 64;
    if (tid < 64) {
        int e = perm[e0 + tid];
        eS[tid] = e; colS[tid] = col[e]; rowS[tid] = row[e];
    }
    for (int t = tid; t < 256; t += 256) Pw[t] = mW1e[t];
    __syncthreads();
    if (tid < 128) { Es[tid>>1][tid&1] = ef[(size_t)eS[tid>>1]*2 + (tid&1)]; }
    __syncthreads();

    int mP = (tid >> 6)*16 + (tid & 15);
    int ccB = ((tid & 63) >> 4)*8;
    float e0v = Es[mP][0], e1v = Es[mP][1];
    #pragma unroll
    for (int s4 = 0; s4 < 4; ++s4) {
        int cc = s4*32 + ccB;
        uint4 ra = *(const uint4*)(RM + (size_t)rowS[mP]*HD + cc);
        uint4 cb = *(const uint4*)(CM + (size_t)colS[mP]*HD + cc);
        float rf[8], cf[8];
        unp8(ra, rf); unp8(cb, cf);
        float4 o0, o1;
        o0.x = fmaxf(rf[0]+cf[0]+e0v*Pw[cc+0]+e1v*Pw[128+cc+0], 0.f);
        o0.y = fmaxf(rf[1]+cf[1]+e0v*Pw[cc+1]+e1v*Pw[128+cc+1], 0.f);
        o0.z = fmaxf(rf[2]+cf[2]+e0v*Pw[cc+2]+e1v*Pw[128+cc+2], 0.f);
        o0.w = fmaxf(rf[3]+cf[3]+e0v*Pw[cc+3]+e1v*Pw[128+cc+3], 0.f);
        o1.x = fmaxf(rf[4]+cf[4]+e0v*Pw[cc+4]+e1v*Pw[128+cc+4], 0.f);
        o1.y = fmaxf(rf[5]+cf[5]+e0v*Pw[cc+5]+e1v*Pw[128+cc+5], 0.f);
        o1.z = fmaxf(rf[6]+cf[6]+e0v*Pw[cc+6]+e1v*Pw[128+cc+6], 0.f);
        o1.w = fmaxf(rf[7]+cf[7]+e0v*Pw[cc+7]+e1v*Pw[128+cc+7], 0.f);
        *(float4*)&Ms[mP][cc]   = o0;
        *(float4*)&Ms[mP][cc+4] = o1;
    }
    __syncthreads();

    {
        int n = tid & 127, hh = tid >> 7;
        int m0 = hh*32;
        float accv = 0.f;
        int cur = colS[m0];
        for (int m = m0; m < m0 + 32; ++m) {
            int cm = colS[m];
            if (cm != cur) {
                atomicAdd(&agg[(size_t)cur*HD + n], accv);
                accv = 0.f; cur = cm;
            }
            accv += Ms[m][n];
        }
        atomicAdd(&agg[(size_t)cur*HD + n], accv);
    }
}

union MsHFu { uint4 HF4[1024]; float Ms[64][132]; };

// ---------------------------------------------------------------- FUSED edge(l) + msg(l+1) h-aggregation
__global__ __launch_bounds__(256) void k_edgemsg2(
    const unsigned short* __restrict__ RE, const unsigned short* __restrict__ CE,
    const unsigned short* __restrict__ RM, const unsigned short* __restrict__ CM,
    float* __restrict__ ef,
    const int* __restrict__ row, const int* __restrict__ col,
    const int* __restrict__ perm,
    const float* __restrict__ eW1e,
    const unsigned short* __restrict__ eW2p, const float* __restrict__ eB2,
    const float* __restrict__ elg, const float* __restrict__ elb,
    const float* __restrict__ mW1e,
    float* __restrict__ agg, int writeEf)
{
    __shared__ MsHFu MU;
    __shared__ float Pew[256], Pmw[256];
    __shared__ float Es[64][2];
    __shared__ int colS[64], rowS[64], eS[64];
    int tid = threadIdx.x;
    int e0  = blockIdx.x * 64;
    if (tid < 64) {
        int e = perm[e0 + tid];
        eS[tid] = e; colS[tid] = col[e]; rowS[tid] = row[e];
    }
    for (int t = tid; t < 256; t += 256) { Pew[t] = eW1e[t]; Pmw[t] = mW1e[t]; }
    __syncthreads();

    int mP = (tid >> 6)*16 + (tid & 15);
    int ccB = ((tid & 63) >> 4)*8;
    uint4 regR[4], regC[4];
    #pragma unroll
    for (int s4 = 0; s4 < 4; ++s4) {
        int cc = s4*32 + ccB;
        regR[s4] = *(const uint4*)(RM + (size_t)rowS[mP]*HD + cc);
        regC[s4] = *(const uint4*)(CM + (size_t)colS[mP]*HD + cc);
    }
    if (tid < 128) { Es[tid>>1][tid&1] = ef[(size_t)eS[tid>>1]*2 + (tid&1)]; }
    __syncthreads();

    int lane = tid & 63, wave = tid >> 6;
    int lr = lane & 15, lq = lane >> 4;

    {
        float e0v = Es[mP][0], e1v = Es[mP][1];
        #pragma unroll
        for (int s4 = 0; s4 < 4; ++s4) {
            int s = tid + s4*256;
            int cc = s4*32 + ccB;
            uint4 ra = *(const uint4*)(RE + (size_t)rowS[mP]*HD + cc);
            uint4 cb = *(const uint4*)(CE + (size_t)colS[mP]*HD + cc);
            float rf[8], cf[8];
            unp8(ra, rf); unp8(cb, cf);
            unsigned short hb[8];
            #pragma unroll
            for (int j = 0; j < 8; ++j) {
                int n = cc + j;
                float o = rf[j] + cf[j] + e0v*Pew[n] + e1v*Pew[128+n];
                hb[j] = f2bf(fmaxf(o, 0.f));
            }
            uint4 pk;
            pk.x = hb[0] | ((unsigned)hb[1]<<16); pk.y = hb[2] | ((unsigned)hb[3]<<16);
            pk.z = hb[4] | ((unsigned)hb[5]<<16); pk.w = hb[6] | ((unsigned)hb[7]<<16);
            MU.HF4[s] = pk;
        }
    }
    __syncthreads();

    f32x4 a2 = (f32x4){0.f,0.f,0.f,0.f};
    for (int ks = 0; ks < 4; ++ks) {
        short8 a = *(const short8*)&MU.HF4[(ks*4 + wave)*64 + lane];
        short8 b = *(const short8*)(eW2p + (size_t)(ks*64 + lane)*8);
        a2 = __builtin_amdgcn_mfma_f32_16x16x32_bf16(a, b, a2, 0,0,0);
    }
    if (lr < 2) {
        int d = lr;
        float bb = eB2[d];
        float gg = elg[d], bl = elb[d];
        #pragma unroll
        for (int r = 0; r < 4; ++r) {
            int m = wave*16 + lq*4 + r;
            float rv = Es[m][d] + a2[r] + bb;
            float other = __shfl_xor(rv, 1, 64);
            float mm = 0.5f*(rv + other);
            float dr = rv - mm, dro = other - mm;
            float vv = 0.5f*(dr*dr + dro*dro);
            float outv = dr / sqrtf(vv + 1e-5f) * gg + bl;
            Es[m][d] = outv;
            if (writeEf) ef[(size_t)eS[m]*2 + d] = outv;
        }
    }
    __syncthreads();

    {
        float e0v = Es[mP][0], e1v = Es[mP][1];
        #pragma unroll
        for (int s4 = 0; s4 < 4; ++s4) {
            int cc = s4*32 + ccB;
            float rf[8], cf[8];
            unp8(regR[s4], rf); unp8(regC[s4], cf);
            float4 o0, o1;
            o0.x = fmaxf(rf[0]+cf[0]+e0v*Pmw[cc+0]+e1v*Pmw[128+cc+0], 0.f);
            o0.y = fmaxf(rf[1]+cf[1]+e0v*Pmw[cc+1]+e1v*Pmw[128+cc+1], 0.f);
            o0.z = fmaxf(rf[2]+cf[2]+e0v*Pmw[cc+2]+e1v*Pmw[128+cc+2], 0.f);
            o0.w = fmaxf(rf[3]+cf[3]+e0v*Pmw[cc+3]+e1v*Pmw[128+cc+3], 0.f);
            o1.x = fmaxf(rf[4]+cf[4]+e0v*Pmw[cc+4]+e1v*Pmw[128+cc+4], 0.f);
            o1.y = fmaxf(rf[5]+cf[5]+e0v*Pmw[cc+5]+e1v*Pmw[128+cc+5], 0.f);
            o1.z = fmaxf(rf[6]+cf[6]+e0v*Pmw[cc+6]+e1v*Pmw[128+cc+6], 0.f);
            o1.w = fmaxf(rf[7]+cf[7]+e0v*Pmw[cc+7]+e1v*Pmw[128+cc+7], 0.f);
            *(float4*)&MU.Ms[mP][cc]   = o0;
            *(float4*)&MU.Ms[mP][cc+4] = o1;
        }
    }
    __syncthreads();

    {
        int n = tid & 127, hh = tid >> 7;
        int m0 = hh*32;
        float accv = 0.f;
        int cur = colS[m0];
        for (int m = m0; m < m0 + 32; ++m) {
            int cm = colS[m];
            if (cm != cur) {
                atomicAdd(&agg[(size_t)cur*HD + n], accv);
                accv = 0.f; cur = cm;
            }
            accv += MU.Ms[m][n];
        }
        atomicAdd(&agg[(size_t)cur*HD + n], accv);
    }
}

// ---------------------------------------------------------------- node update
union XRu { unsigned short Xs[64][264]; float Rs[64][132]; };

__global__ __launch_bounds__(256) void k_node_mfma(
    float* __restrict__ u, unsigned short* __restrict__ u16,
    float* __restrict__ agg, const int* __restrict__ cnt,
    const unsigned short* __restrict__ W1p, const float* __restrict__ B1,
    const unsigned short* __restrict__ W2p, const float* __restrict__ B2,
    const float* __restrict__ lg, const float* __restrict__ lb,
    const unsigned short* __restrict__ mW2pC, const float* __restrict__ mB2C,
    int doExtra,
    const unsigned short* __restrict__ eW1p, const float* __restrict__ eB1c,
    const unsigned short* __restrict__ mW1pN, const float* __restrict__ mB1N,
    unsigned short* __restrict__ RE, unsigned short* __restrict__ CE,
    unsigned short* __restrict__ RM, unsigned short* __restrict__ CM)
{
    __shared__ XRu XR;
    __shared__ HUu HU;
    __shared__ float red[64][4];
    __shared__ float mstat[64], sstat[64];
    __shared__ float invS[64], fS[64];
    int tid = threadIdx.x;
    int n0  = blockIdx.x * 64;
    for (int t = tid; t < 1024; t += 256) {
        int el = t >> 4, kc = t & 15;
        uint4 v = *(const uint4*)(u16 + (size_t)(n0+el)*HD + kc*8);
        *(uint4*)&XR.Xs[el][kc*8] = v;
    }
    if (tid < 64) {
        int c = cnt[n0 + tid];
        invS[tid] = 1.f / fmaxf((float)c, 1.f);
        fS[tid] = (c > 0) ? 1.f : 0.f;
    }
    for (int t = tid; t < 1024; t += 256) {
        int lane_s = t & 63, ksmt = t >> 6;
        int ks = ksmt >> 2, mt = ksmt & 3;
        int el = mt*16 + (lane_s & 15);
        int cc = ks*32 + (lane_s >> 4)*8;
        const float* src = agg + (size_t)(n0+el)*HD + cc;
        float4 a = *(const float4*)src;
        float4 b = *(const float4*)(src + 4);
        uint4 pk;
        pk.x = f2bf(a.x) | ((unsigned)f2bf(a.y) << 16);
        pk.y = f2bf(a.z) | ((unsigned)f2bf(a.w) << 16);
        pk.z = f2bf(b.x) | ((unsigned)f2bf(b.y) << 16);
        pk.w = f2bf(b.z) | ((unsigned)f2bf(b.w) << 16);
        HU.UF4[t] = pk;
    }
    __syncthreads();

    int lane = tid & 63, wave = tid >> 6;
    int lr = lane & 15, lq = lane >> 4;
    f32x4 acc[8];

    #pragma unroll
    for (int i = 0; i < 8; ++i) acc[i] = (f32x4){0.f,0.f,0.f,0.f};
    for (int ks = 0; ks < 4; ++ks) {
        short8 a0 = *(const short8*)&HU.UF4[(ks*4+0)*64 + lane];
        short8 a1 = *(const short8*)&HU.UF4[(ks*4+1)*64 + lane];
        short8 a2 = *(const short8*)&HU.UF4[(ks*4+2)*64 + lane];
        short8 a3 = *(const short8*)&HU.UF4[(ks*4+3)*64 + lane];
        short8 b0 = *(const short8*)(mW2pC + (size_t)(((wave*2+0)*4 + ks)*64 + lane)*8);
        short8 b1 = *(const short8*)(mW2pC + (size_t)(((wave*2+1)*4 + ks)*64 + lane)*8);
        acc[0] = __builtin_amdgcn_mfma_f32_16x16x32_bf16(a0, b0, acc[0], 0,0,0);
        acc[1] = __builtin_amdgcn_mfma_f32_16x16x32_bf16(a0, b1, acc[1], 0,0,0);
        acc[2] = __builtin_amdgcn_mfma_f32_16x16x32_bf16(a1, b0, acc[2], 0,0,0);
        acc[3] = __builtin_amdgcn_mfma_f32_16x16x32_bf16(a1, b1, acc[3], 0,0,0);
        acc[4] = __builtin_amdgcn_mfma_f32_16x16x32_bf16(a2, b0, acc[4], 0,0,0);
        acc[5] = __builtin_amdgcn_mfma_f32_16x16x32_bf16(a2, b1, acc[5], 0,0,0);
        acc[6] = __builtin_amdgcn_mfma_f32_16x16x32_bf16(a3, b0, acc[6], 0,0,0);
        acc[7] = __builtin_amdgcn_mfma_f32_16x16x32_bf16(a3, b1, acc[7], 0,0,0);
    }
    #pragma unroll
    for (int b = 0; b < 2; ++b) {
        int n = (wave*2 + b)*16 + lr;
        float bb = mB2C[n];
        #pragma unroll
        for (int mt = 0; mt < 4; ++mt) {
            f32x4 v = acc[mt*2 + b];
            #pragma unroll
            for (int r = 0; r < 4; ++r) {
                int m = mt*16 + lq*4 + r;
                float val = v[r]*invS[m] + fS[m]*bb;
                unsigned hv = f2bf(val);
                unsigned ph = (unsigned)__shfl_xor((int)hv, 1, 64);
                if (!(lr & 1))
                    *(unsigned*)&XR.Xs[m][128 + n] = hv | (ph << 16);
            }
        }
    }
    __syncthreads();

    #pragma unroll
    for (int i = 0; i < 8; ++i) acc[i] = (f32x4){0.f,0.f,0.f,0.f};
    for (int ks = 0; ks < 8; ++ks) {
        short8 a0 = *(const short8*)&XR.Xs[ 0 + lr][ks*32 + lq*8];
        short8 a1 = *(const short8*)&XR.Xs[16 + lr][ks*32 + lq*8];
        short8 a2 = *(const short8*)&XR.Xs[32 + lr][ks*32 + lq*8];
        short8 a3 = *(const short8*)&XR.Xs[48 + lr][ks*32 + lq*8];
        short8 b0 = *(const short8*)(W1p + (size_t)(((wave*2+0)*8 + ks)*64 + lane)*8);
        short8 b1 = *(const short8*)(W1p + (size_t)(((wave*2+1)*8 + ks)*64 + lane)*8);
        acc[0] = __builtin_amdgcn_mfma_f32_16x16x32_bf16(a0, b0, acc[0], 0,0,0);
        acc[1] = __builtin_amdgcn_mfma_f32_16x16x32_bf16(a0, b1, acc[1], 0,0,0);
        acc[2] = __builtin_amdgcn_mfma_f32_16x16x32_bf16(a1, b0, acc[2], 0,0,0);
        acc[3] = __builtin_amdgcn_mfma_f32_16x16x32_bf16(a1, b1, acc[3], 0,0,0);
        acc[4] = __builtin_amdgcn_mfma_f32_16x16x32_bf16(a2, b0, acc[4], 0,0,0);
        acc[5] = __builtin_amdgcn_mfma_f32_16x16x32_bf16(a2, b1, acc[5], 0,0,0);
        acc[6] = __builtin_amdgcn_mfma_f32_16x16x32_bf16(a3, b0, acc[6], 0,0,0);
        acc[7] = __builtin_amdgcn_mfma_f32_16x16x32_bf16(a3, b1, acc[7], 0,0,0);
    }
    #pragma unroll
    for (int b = 0; b < 2; ++b) {
        int n = (wave*2 + b)*16 + lr;
        float bb = B1[n];
        #pragma unroll
        for (int mt = 0; mt < 4; ++mt) {
            f32x4 v = acc[mt*2 + b];
            #pragma unroll
            for (int r = 0; r < 4; ++r) {
                int m = mt*16 + lq*4 + r;
                HU.Hs[m][n] = f2bf(fmaxf(v[r] + bb, 0.f));
            }
        }
    }
    __syncthreads();

    #pragma unroll
    for (int i = 0; i < 8; ++i) acc[i] = (f32x4){0.f,0.f,0.f,0.f};
    for (int ks = 0; ks < 4; ++ks) {
        short8 a0 = *(const short8*)&HU.Hs[ 0 + lr][ks*32 + lq*8];
        short8 a1 = *(const short8*)&HU.Hs[16 + lr][ks*32 + lq*8];
        short8 a2 = *(const short8*)&HU.Hs[32 + lr][ks*32 + lq*8];
        short8 a3 = *(const short8*)&HU.Hs[48 + lr][ks*32 + lq*8];
        short8 b0 = *(const short8*)(W2p + (size_t)(((wave*2+0)*4 + ks)*64 + lane)*8);
        short8 b1 = *(const short8*)(W2p + (size_t)(((wave*2+1)*4 + ks)*64 + lane)*8);
        acc[0] = __builtin_amdgcn_mfma_f32_16x16x32_bf16(a0, b0, acc[0], 0,0,0);
        acc[1] = __builtin_amdgcn_mfma_f32_16x16x32_bf16(a0, b1, acc[1], 0,0,0);
        acc[2] = __builtin_amdgcn_mfma_f32_16x16x32_bf16(a1, b0, acc[2], 0,0,0);
        acc[3] = __builtin_amdgcn_mfma_f32_16x16x32_bf16(a1, b1, acc[3], 0,0,0);
        acc[4] = __builtin_amdgcn_mfma_f32_16x16x32_bf16(a2, b0, acc[4], 0,0,0);
        acc[5] = __builtin_amdgcn_mfma_f32_16x16x32_bf16(a2, b1, acc[5], 0,0,0);
        acc[6] = __builtin_amdgcn_mfma_f32_16x16x32_bf16(a3, b0, acc[6], 0,0,0);
        acc[7] = __builtin_amdgcn_mfma_f32_16x16x32_bf16(a3, b1, acc[7], 0,0,0);
    }
    #pragma unroll
    for (int b = 0; b < 2; ++b) {
        int n = (wave*2 + b)*16 + lr;
        float bb = B2[n];
        #pragma unroll
        for (int mt = 0; mt < 4; ++mt) {
            f32x4 v = acc[mt*2 + b];
            #pragma unroll
            for (int r = 0; r < 4; ++r) {
                int m = mt*16 + lq*4 + r;
                XR.Rs[m][n] = u[(size_t)(n0+m)*HD + n] + v[r] + bb;
            }
        }
    }
    __syncthreads();
    {
        int m = tid >> 2, p = tid & 3;
        float s = 0.f;
        #pragma unroll 8
        for (int i = 0; i < 32; ++i) s += XR.Rs[m][p*32 + i];
        red[m][p] = s;
    }
    __syncthreads();
    if (tid < 64) mstat[tid] = (red[tid][0]+red[tid][1]+red[tid][2]+red[tid][3]) * (1.f/HD);
    __syncthreads();
    {
        int m = tid >> 2, p = tid & 3;
        float mm = mstat[m];
        float s = 0.f;
        #pragma unroll 8
        for (int i = 0; i < 32; ++i) { float d = XR.Rs[m][p*32 + i] - mm; s += d*d; }
        red[m][p] = s;
    }
    __syncthreads();
    if (tid < 64) sstat[tid] = sqrtf((red[tid][0]+red[tid][1]+red[tid][2]+red[tid][3]) * (1.f/HD) + 1e-5f);
    __syncthreads();
    for (int t = tid; t < 2048; t += 256) {
        int m = t >> 5, q = t & 31;
        int n = q*4;
        float mm = mstat[m], sd = sstat[m];
        float4 g4 = *(const float4*)(lg + n);
        float4 b4 = *(const float4*)(lb + n);
        float o0 = (XR.Rs[m][n+0]-mm)/sd*g4.x + b4.x;
        float o1 = (XR.Rs[m][n+1]-mm)/sd*g4.y + b4.y;
        float o2 = (XR.Rs[m][n+2]-mm)/sd*g4.z + b4.z;
        float o3 = (XR.Rs[m][n+3]-mm)/sd*g4.w + b4.w;
        float4 fo; fo.x=o0; fo.y=o1; fo.z=o2; fo.w=o3;
        *(float4*)(u + (size_t)(n0+m)*HD + n) = fo;
        uint2 pk; pk.x = f2bf(o0) | (f2bf(o1)<<16); pk.y = f2bf(o2) | (f2bf(o3)<<16);
        *(uint2*)(u16 + (size_t)(n0+m)*HD + n) = pk;
        if (doExtra) {
            int ksf = n >> 5, sub = (n >> 3) & 3;
            int slot = (ksf*4 + (m >> 4))*64 + ((m & 15) | (sub << 4));
            unsigned short* UF = (unsigned short*)HU.UF4;
            *(uint2*)&UF[slot*8 + (n & 7)] = pk;
        }
    }
    {
        float4 z; z.x=0.f; z.y=0.f; z.z=0.f; z.w=0.f;
        for (int t = tid; t < 2048; t += 256)
            *(float4*)(agg + (size_t)(n0 + (t>>5))*HD + (t&31)*4) = z;
    }
    if (!doExtra) return;
    __syncthreads();

    for (int g = 0; g < 4; ++g) {
        const unsigned short* Bp = (g < 2) ? eW1p : mW1pN;
        int ksOff = (g & 1) * 4;
        unsigned short* Out = (g == 0) ? RE : (g == 1) ? CE : (g == 2) ? RM : CM;
        const float* bias = (g == 1) ? eB1c : (g == 3) ? mB1N : (const float*)nullptr;
        #pragma unroll
        for (int i = 0; i < 8; ++i) acc[i] = (f32x4){0.f,0.f,0.f,0.f};
        for (int ks = 0; ks < 4; ++ks) {
            short8 a0 = *(const short8*)&HU.UF4[(ks*4+0)*64 + lane];
            short8 a1 = *(const short8*)&HU.UF4[(ks*4+1)*64 + lane];
            short8 a2 = *(const short8*)&HU.UF4[(ks*4+2)*64 + lane];
            short8 a3 = *(const short8*)&HU.UF4[(ks*4+3)*64 + lane];
            short8 b0 = *(const short8*)(Bp + (size_t)(((wave*2+0)*8 + ksOff + ks)*64 + lane)*8);
            short8 b1 = *(const short8*)(Bp + (size_t)(((wave*2+1)*8 + ksOff + ks)*64 + lane)*8);
            acc[0] = __builtin_amdgcn_mfma_f32_16x16x32_bf16(a0, b0, acc[0], 0,0,0);
            acc[1] = __builtin_amdgcn_mfma_f32_16x16x32_bf16(a0, b1, acc[1], 0,0,0);
            acc[2] = __builtin_amdgcn_mfma_f32_16x16x32_bf16(a1, b0, acc[2], 0,0,0);
            acc[3] = __builtin_amdgcn_mfma_f32_16x16x32_bf16(a1, b1, acc[3], 0,0,0);
            acc[4] = __builtin_amdgcn_mfma_f32_16x16x32_bf16(a2, b0, acc[4], 0,0,0);
            acc[5] = __builtin_amdgcn_mfma_f32_16x16x32_bf16(a2, b1, acc[5], 0,0,0);
            acc[6] = __builtin_amdgcn_mfma_f32_16x16x32_bf16(a3, b0, acc[6], 0,0,0);
            acc[7] = __builtin_amdgcn_mfma_f32_16x16x32_bf16(a3, b1, acc[7], 0,0,0);
        }
        #pragma unroll
        for (int b = 0; b < 2; ++b) {
            int n = (wave*2 + b)*16 + lr;
            float bb = bias ? bias[n] : 0.f;
            #pragma unroll
            for (int mt = 0; mt < 4; ++mt) {
                f32x4 v = acc[mt*2 + b];
                #pragma unroll
                for (int r = 0; r < 4; ++r) {
                    int rowp = n0 + mt*16 + lq*4 + r;
                    unsigned hv = f2bf(v[r] + bb);
                    unsigned ph = (unsigned)__shfl_xor((int)hv, 1, 64);
                    if (!(lr & 1))
                        *(unsigned*)&Out[(size_t)rowp*HD + n] = hv | (ph << 16);
                }
            }
        }
    }
}

// ---------------------------------------------------------------- stage 4+5: u3 = LN(MLP(u)), fused coef-weighted pool -> partial
__global__ __launch_bounds__(256) void k_m2_mfma(
    const unsigned short* __restrict__ u16,
    const unsigned short* __restrict__ W1p, const float* __restrict__ B1,
    const unsigned short* __restrict__ W2p, const float* __restrict__ B2,
    const float* __restrict__ lg, const float* __restrict__ lb,
    const float* __restrict__ coef, float* __restrict__ partial)
{
    __shared__ unsigned short Xs[64][136];
    __shared__ unsigned short Hs[64][136];
    __shared__ float Rs[64][132];
    __shared__ float red[64][4];
    __shared__ float mstat[64], sstat[64];
    __shared__ float zp[HD];
    int tid = threadIdx.x;
    int n0  = blockIdx.x * 64;
    if (tid < HD) zp[tid] = 0.f;
    for (int t = tid; t < 1024; t += 256) {
        int el = t >> 4, kc = t & 15;
        uint4 v = *(const uint4*)(u16 + (size_t)(n0+el)*HD + kc*8);
        *(uint4*)&Xs[el][kc*8] = v;
    }
    __syncthreads();

    int lane = tid & 63, wave = tid >> 6;
    int lr = lane & 15, lq = lane >> 4;
    f32x4 acc[8];
    #pragma unroll
    for (int i = 0; i < 8; ++i) acc[i] = (f32x4){0.f,0.f,0.f,0.f};
    for (int ks = 0; ks < 4; ++ks) {
        short8 a0 = *(const short8*)&Xs[ 0 + lr][ks*32 + lq*8];
        short8 a1 = *(const short8*)&Xs[16 + lr][ks*32 + lq*8];
        short8 a2 = *(const short8*)&Xs[32 + lr][ks*32 + lq*8];
        short8 a3 = *(const short8*)&Xs[48 + lr][ks*32 + lq*8];
        short8 b0 = *(const short8*)(W1p + (size_t)(((wave*2+0)*4 + ks)*64 + lane)*8);
        short8 b1 = *(const short8*)(W1p + (size_t)(((wave*2+1)*4 + ks)*64 + lane)*8);
        acc[0] = __builtin_amdgcn_mfma_f32_16x16x32_bf16(a0, b0, acc[0], 0,0,0);
        acc[1] = __builtin_amdgcn_mfma_f32_16x16x32_bf16(a0, b1, acc[1], 0,0,0);
        acc[2] = __builtin_amdgcn_mfma_f32_16x16x32_bf16(a1, b0, acc[2], 0,0,0);
        acc[3] = __builtin_amdgcn_mfma_f32_16x16x32_bf16(a1, b1, acc[3], 0,0,0);
        acc[4] = __builtin_amdgcn_mfma_f32_16x16x32_bf16(a2, b0, acc[4], 0,0,0);
        acc[5] = __builtin_amdgcn_mfma_f32_16x16x32_bf16(a2, b1, acc[5], 0,0,0);
        acc[6] = __builtin_amdgcn_mfma_f32_16x16x32_bf16(a3, b0, acc[6], 0,0,0);
        acc[7] = __builtin_amdgcn_mfma_f32_16x16x32_bf16(a3, b1, acc[7], 0,0,0);
    }
    #pragma unroll
    for (int b = 0; b < 2; ++b) {
        int n = (wave*2 + b)*16 + lr;
        float bb = B1[n];
        #pragma unroll
        for (int mt = 0; mt < 4; ++mt) {
            f32x4 v = acc[mt*2 + b];
            #pragma unroll
            for (int r = 0; r < 4; ++r) {
                int m = mt*16 + lq*4 + r;
                Hs[m][n] = f2bf(fmaxf(v[r] + bb, 0.f));
            }
        }
    }
    __syncthreads();

    #pragma unroll
    for (int i = 0; i < 8; ++i) acc[i] = (f32x4){0.f,0.f,0.f,0.f};
    for (int ks = 0; ks < 4; ++ks) {
        short8 a0 = *(const short8*)&Hs[ 0 + lr][ks*32 + lq*8];
        short8 a1 = *(const short8*)&Hs[16 + lr][ks*32 + lq*8];
        short8 a2 = *(const short8*)&Hs[32 + lr][ks*32 + lq*8];
        short8 a3 = *(const short8*)&Hs[48 + lr][ks*32 + lq*8];
        short8 b0 = *(const short8*)(W2p + (size_t)(((wave*2+0)*4 + ks)*64 + lane)*8);
        short8 b1 = *(const short8*)(W2p + (size_t)(((wave*2+1)*4 + ks)*64 + lane)*8);
        acc[0] = __builtin_amdgcn_mfma_f32_16x16x32_bf16(a0, b0, acc[0], 0,0,0);
        acc[1] = __builtin_amdgcn_mfma_f32_16x16x32_bf16(a0, b1, acc[1], 0,0,0);
        acc[2] = __builtin_amdgcn_mfma_f32_16x16x32_bf16(a1, b0, acc[2], 0,0,0);
        acc[3] = __builtin_amdgcn_mfma_f32_16x16x32_bf16(a1, b1, acc[3], 0,0,0);
        acc[4] = __builtin_amdgcn_mfma_f32_16x16x32_bf16(a2, b0, acc[4], 0,0,0);
        acc[5] = __builtin_amdgcn_mfma_f32_16x16x32_bf16(a2, b1, acc[5], 0,0,0);
        acc[6] = __builtin_amdgcn_mfma_f32_16x16x32_bf16(a3, b0, acc[6], 0,0,0);
        acc[7] = __builtin_amdgcn_mfma_f32_16x16x32_bf16(a3, b1, acc[7], 0,0,0);
    }
    #pragma unroll
    for (int b = 0; b < 2; ++b) {
        int n = (wave*2 + b)*16 + lr;
        float bb = B2[n];
        #pragma unroll
        for (int mt = 0; mt < 4; ++mt) {
            f32x4 v = acc[mt*2 + b];
            #pragma unroll
            for (int r = 0; r < 4; ++r) {
                int m = mt*16 + lq*4 + r;
                Rs[m][n] = v[r] + bb;
            }
        }
    }
    __syncthreads();
    {
        int m = tid >> 2, p = tid & 3;
        float s = 0.f;
        #pragma unroll 8
        for (int i = 0; i < 32; ++i) s += Rs[m][p*32 + i];
        red[m][p] = s;
    }
    __syncthreads();
    if (tid < 64) mstat[tid] = (red[tid][0]+red[tid][1]+red[tid][2]+red[tid][3]) * (1.f/HD);
    __syncthreads();
    {
        int m = tid >> 2, p = tid & 3;
        float mm = mstat[m];
        float s = 0.f;
        #pragma unroll 8
        for (int i = 0; i < 32; ++i) { float d = Rs[m][p*32 + i] - mm; s += d*d; }
        red[m][p] = s;
    }
    __syncthreads();
    if (tid < 64) sstat[tid] = sqrtf((red[tid][0]+red[tid][1]+red[tid][2]+red[tid][3]) * (1.f/HD) + 1e-5f);
    __syncthreads();
    {
        float4 a4; a4.x=0.f; a4.y=0.f; a4.z=0.f; a4.w=0.f;
        int q = tid & 31;
        int n = q*4;
        float4 g4 = *(const float4*)(lg + n);
        float4 b4 = *(const float4*)(lb + n);
        for (int t = tid; t < 2048; t += 256) {
            int m = t >> 5;
            float mm = mstat[m], sd = sstat[m];
            float cw = coef[n0 + m];
            float o0 = (Rs[m][n+0]-mm)/sd*g4.x + b4.x;
            float o1 = (Rs[m][n+1]-mm)/sd*g4.y + b4.y;
            float o2 = (Rs[m][n+2]-mm)/sd*g4.z + b4.z;
            float o3 = (Rs[m][n+3]-mm)/sd*g4.w + b4.w;
            a4.x += cw*o0; a4.y += cw*o1; a4.z += cw*o2; a4.w += cw*o3;
        }
        atomicAdd(&zp[n+0], a4.x);
        atomicAdd(&zp[n+1], a4.y);
        atomicAdd(&zp[n+2], a4.z);
        atomicAdd(&zp[n+3], a4.w);
    }
    __syncthreads();
    if (tid < HD) partial[(size_t)blockIdx.x*HD + tid] = zp[tid];
}

// ---------------------------------------------------------------- stage 6: reduce partials + output MLP
__global__ __launch_bounds__(128) void k_out(
    const float* __restrict__ partial,
    const float* __restrict__ w1, const float* __restrict__ b1,
    const float* __restrict__ w2, const float* __restrict__ b2,
    float* __restrict__ out)
{
    __shared__ float zs[HD];
    __shared__ float hs[HD];
    int j = threadIdx.x;
    float s = 0.f;
    for (int p = 0; p < NN/64; ++p) s += partial[(size_t)p*HD + j];
    zs[j] = s * (1.f/NRED);
    __syncthreads();
    float o = b1[j];
    #pragma unroll 8
    for (int k = 0; k < HD; ++k) o += zs[k]*w1[k*HD + j];
    hs[j] = fmaxf(o, 0.f);
    __syncthreads();
    if (j < LATD) {
        float o2 = b2[j];
        #pragma unroll 8
        for (int k = 0; k < HD; ++k) o2 += hs[k]*w2[k*LATD + j];
        out[j] = o2;
    }
}

extern "C" void kernel_launch(void* const* d_in, const int* in_sizes, int n_in,
                              void* d_out, int out_size, void* d_ws, size_t ws_size,
                              hipStream_t stream)
{
    const float* x    = (const float*)d_in[0];
    const float* pos  = (const float*)d_in[1];
    const int*   eidx = (const int*)d_in[2];
    const int* row = eidx;
    const int* col = eidx + NEDGE;
    const float* m0_w1 = (const float*)d_in[3];
    const float* m0_b1 = (const float*)d_in[4];
    const float* m0_w2 = (const float*)d_in[5];
    const float* m0_b2 = (const float*)d_in[6];
    const float* ln0_g = (const float*)d_in[7];
    const float* ln0_b = (const float*)d_in[8];
    const float* m1_w1 = (const float*)d_in[9];
    const float* m1_b1 = (const float*)d_in[10];
    const float* m1_w2 = (const float*)d_in[11];
    const float* m1_b2 = (const float*)d_in[12];
    const float* ln1_g = (const float*)d_in[13];
    const float* ln1_b = (const float*)d_in[14];
    const float* g_msg_w1  = (const float*)d_in[15];
    const float* g_msg_b1  = (const float*)d_in[16];
    const float* g_msg_w2  = (const float*)d_in[17];
    const float* g_msg_b2  = (const float*)d_in[18];
    const float* g_node_w1 = (const float*)d_in[19];
    const float* g_node_b1 = (const float*)d_in[20];
    const float* g_node_w2 = (const float*)d_in[21];
    const float* g_node_b2 = (const float*)d_in[22];
    const float* g_edge_w1 = (const float*)d_in[23];
    const float* g_edge_b1 = (const float*)d_in[24];
    const float* g_edge_w2 = (const float*)d_in[25];
    const float* g_edge_b2 = (const float*)d_in[26];
    const float* g_lnn_g   = (const float*)d_in[27];
    const float* g_lnn_b   = (const float*)d_in[28];
    const float* g_lne_g   = (const float*)d_in[29];
    const float* g_lne_b   = (const float*)d_in[30];
    const float* m2_w1 = (const float*)d_in[31];
    const float* m2_b1 = (const float*)d_in[32];
    const float* m2_w2 = (const float*)d_in[33];
    const float* m2_b2 = (const float*)d_in[34];
    const float* ln2_g = (const float*)d_in[35];
    const float* ln2_b = (const float*)d_in[36];
    const float* op_w1 = (const float*)d_in[37];
    const float* op_b1 = (const float*)d_in[38];
    const float* op_w2 = (const float*)d_in[39];
    const float* op_b2 = (const float*)d_in[40];

    float* u    = (float*)d_ws;                       // NN*HD f32
    float* ef   = u + (size_t)NN*HD;                  // NEDGE*2
    float* agg  = ef + (size_t)NEDGE*2;               // NN*HD (h-sums)
    int*   cnt  = (int*)(agg + (size_t)NN*HD);        // NN
    int*   gcnt = cnt + NN;                           // 1024
    float* coef = (float*)(gcnt + 1024);              // NN
    int*   head = (int*)(coef + NN);                  // NN
    int*   perm = head + NN;                          // NEDGE
    float* partial = (float*)(perm + NEDGE);          // (NN/64)*HD
    int*   gstart = (int*)(partial + (NN/64)*HD);     // 1026
    int*   ghead  = gstart + 1026;                    // 1024
    int*   pidx   = ghead + 1024;                     // NN
    float2* psort = (float2*)(pidx + NN);             // NN float2
    unsigned short* u16 = (unsigned short*)(psort + NN);  // NN*HD bf16
    unsigned short* packs = u16 + (size_t)NN*HD;      // PK_TOTAL shorts
    unsigned short* msgW1p  = packs;
    unsigned short* msgW2p  = packs + 98304;
    unsigned short* edgeW1p = packs + 147456;
    unsigned short* nodeW1p = packs + 245760;
    unsigned short* nodeW2p = packs + 344064;
    unsigned short* edgeW2p = packs + 393216;
    unsigned short* m0w2p   = packs + 399360;
    unsigned short* m2w1p   = packs + 415744;
    unsigned short* m2w2p   = packs + 432128;
    unsigned short* RE = packs + PK_TOTAL;            // NN*HD bf16 each
    unsigned short* CE = RE + (size_t)NN*HD;
    unsigned short* RM = CE + (size_t)NN*HD;
    unsigned short* CM = RM + (size_t)NN*HD;

    k_pack_all<<<(PK_TOTAL + 255)/256, 256, 0, stream>>>(
        g_msg_w1, g_msg_w2, g_edge_w1, g_node_w1, g_node_w2, g_edge_w2,
        m0_w2, m2_w1, m2_w2, packs);

    hipMemsetAsync(cnt, 0, (NN + 1024 + NN)*sizeof(int), stream);

    k_nenc_mfma<<<NN/64, 256, 0, stream>>>(x, m0_w1, m0_b1, m0w2p, m0_b2, ln0_g, ln0_b,
                                           msgW1p, g_msg_b1, u, u16, RM, CM, agg);
    k_edge_enc<<<NEDGE/256, 256, 0, stream>>>(pos, row, col, m1_w1, m1_b1, m1_w2, m1_b2,
                                              ln1_g, ln1_b, ef);

    k_count2<<<NEDGE/256, 256, 0, stream>>>(col, pos, cnt, gcnt);
    k_scan2<<<2, 256, 0, stream>>>(cnt, head, gcnt, gstart, ghead);
    k_scatter2<<<NEDGE/256, 256, 0, stream>>>(col, pos, head, perm, ghead, psort, pidx);
    k_knnsel<<<NRED/256, 256, 0, stream>>>(pos, gstart, psort, pidx, coef);

    // layer 0: h-aggregation
    k_hagg0<<<NEDGE/64, 256, 0, stream>>>(RM, CM, ef, row, col, perm,
        g_msg_w1 + 256*HD, agg);
    k_node_mfma<<<NN/64, 256, 0, stream>>>(u, u16, agg, cnt,
        nodeW1p, g_node_b1, nodeW2p, g_node_b2, g_lnn_g, g_lnn_b,
        msgW2p, g_msg_b2,
        1, edgeW1p + 0*32768, g_edge_b1 + 0*HD, msgW1p + 1*32768, g_msg_b1 + 1*HD,
        RE, CE, RM, CM);

    // fused edge(l) + msg(l+1); edge(2) is dead code
    for (int l = 0; l < NLAYER-1; ++l) {
        k_edgemsg2<<<NEDGE/64, 256, 0, stream>>>(RE, CE, RM, CM, ef, row, col, perm,
            g_edge_w1 + (size_t)l*258*HD + 256*HD,
            edgeW2p + l*2048, g_edge_b2 + l*2, g_lne_g + l*2, g_lne_b + l*2,
            g_msg_w1 + (size_t)(l+1)*258*HD + 256*HD,
            agg, (l == 0) ? 1 : 0);
        int doExtra = (l == 0) ? 1 : 0;
        k_node_mfma<<<NN/64, 256, 0, stream>>>(u, u16, agg, cnt,
            nodeW1p + (l+1)*32768, g_node_b1 + (l+1)*HD,
            nodeW2p + (l+1)*16384, g_node_b2 + (l+1)*HD,
            g_lnn_g + (l+1)*HD, g_lnn_b + (l+1)*HD,
            msgW2p + (l+1)*16384, g_msg_b2 + (l+1)*HD,
            doExtra, edgeW1p + 1*32768, g_edge_b1 + 1*HD, msgW1p + 2*32768, g_msg_b1 + 2*HD,
            RE, CE, RM, CM);
    }

    k_m2_mfma<<<NN/64, 256, 0, stream>>>(u16, m2w1p, m2_b1, m2w2p, m2_b2, ln2_g, ln2_b,
                                         coef, partial);
    k_out<<<1, 128, 0, stream>>>(partial, op_w1, op_b1, op_w2, op_b2, (float*)d_out);
}